// Round 2
// baseline (612.168 us; speedup 1.0000x reference)
//
#include <hip/hip_runtime.h>
#include <hip/hip_bf16.h>

#define B_  4
#define L_  2048
#define D_  512
#define H_  8
#define HD_ 64
#define M_  (B_ * L_)   // 8192

typedef __bf16 bf16;
typedef __attribute__((ext_vector_type(8))) __bf16 bf16x8;
typedef __attribute__((ext_vector_type(4))) float  f32x4;

__device__ __forceinline__ f32x4 mfma16(bf16x8 a, bf16x8 b, f32x4 c) {
    return __builtin_amdgcn_mfma_f32_16x16x32_bf16(a, b, c, 0, 0, 0);
}

__device__ __forceinline__ bf16x8 cvt8(float4 x0, float4 x1) {
    bf16x8 t;
    t[0] = (bf16)x0.x; t[1] = (bf16)x0.y; t[2] = (bf16)x0.z; t[3] = (bf16)x0.w;
    t[4] = (bf16)x1.x; t[5] = (bf16)x1.y; t[6] = (bf16)x1.z; t[7] = (bf16)x1.w;
    return t;
}

// C[M,N] = relu(X[M,K] @ W[N,K]^T + b[N]) * postmul;  M=8192, N=K=512.
// Wave: 16m x 64n. Block: 512 thr = 8 waves -> 64m x 128n. grid (M/64, N/128).
// OUT_MODE 0: bf16, head layout [B,H,L,HD]
// OUT_MODE 1: bf16, transposed head layout [B,H,HD,L]
// OUT_MODE 2: fp32, row-major [M,N]  (final output, postmul ignored =1)
template<bool A_BF16, int OUT_MODE>
__global__ __launch_bounds__(512) void proj_kernel(
    const void* __restrict__ Xv, const float* __restrict__ W,
    const float* __restrict__ bias, void* __restrict__ outv, float postmul)
{
    const int wave = threadIdx.x >> 6;
    const int lane = threadIdx.x & 63;
    const int quad = lane >> 4;
    const int l15  = lane & 15;
    const int m_base = blockIdx.x * 64 + (wave & 3) * 16;
    const int n_base = blockIdx.y * 128 + (wave >> 2) * 64;

    const float* Xf = (const float*)Xv;
    const bf16*  Xb = (const bf16*)Xv;

    f32x4 acc[4];
#pragma unroll
    for (int ni = 0; ni < 4; ni++) acc[ni] = (f32x4){0.f, 0.f, 0.f, 0.f};

    auto loadA = [&](int k0) -> bf16x8 {
        const size_t off = (size_t)(m_base + l15) * D_ + k0 + quad * 8;
        if (A_BF16) return *(const bf16x8*)(Xb + off);
        const float4* p = (const float4*)(Xf + off);
        return cvt8(p[0], p[1]);
    };
    auto loadB = [&](int ni, int k0) -> bf16x8 {
        const float4* p = (const float4*)(W + (size_t)(n_base + ni * 16 + l15) * D_ + k0 + quad * 8);
        return cvt8(p[0], p[1]);
    };

    // Software-pipelined k-loop: prefetch k-step i+1 while MFMAing i.
    bf16x8 aC = loadA(0);
    bf16x8 bC[4] = {loadB(0, 0), loadB(1, 0), loadB(2, 0), loadB(3, 0)};
    for (int ks = 0; ks < 16; ks++) {
        const int kn = (ks < 15 ? ks + 1 : 15) * 32;  // last prefetch redundant, in-bounds
        bf16x8 aN = loadA(kn);
        bf16x8 bN[4] = {loadB(0, kn), loadB(1, kn), loadB(2, kn), loadB(3, kn)};
#pragma unroll
        for (int ni = 0; ni < 4; ni++) acc[ni] = mfma16(aC, bC[ni], acc[ni]);
        aC = aN;
#pragma unroll
        for (int ni = 0; ni < 4; ni++) bC[ni] = bN[ni];
    }

#pragma unroll
    for (int ni = 0; ni < 4; ni++)
#pragma unroll
        for (int r = 0; r < 4; r++) {
            const int row = m_base + quad * 4 + r;
            const int col = n_base + ni * 16 + l15;
            float v = acc[ni][r] + bias[col];
            v = fmaxf(v, 0.0f);
            if (OUT_MODE == 2) {
                ((float*)outv)[(size_t)row * D_ + col] = v;
            } else {
                v *= postmul;
                const int b = row >> 11, l = row & (L_ - 1);
                const int h = col >> 6,  hd = col & (HD_ - 1);
                size_t idx;
                if (OUT_MODE == 0)
                    idx = ((size_t)(b * H_ + h) * L_ + l) * HD_ + hd;
                else
                    idx = ((size_t)(b * H_ + h) * HD_ + hd) * L_ + l;
                ((bf16*)outv)[idx] = (bf16)v;
            }
        }
}

// Flash attention, max-free (scores >= 0 because q,k are post-ReLU, so
// exp2 of the pre-scaled score is in [1, ~2^15] -- no overflow, sum >= L).
// qh pre-scaled by (1/sqrt(512))*log2(e) in its projection.
// Wave: 16 q-rows x 1024 j-cols (half of L). Waves (2w, 2w+1) share q-rows
// and split j; unnormalized O and l combine additively through LDS.
// grid = (L/32, B*H), block = 256 (4 waves).
__global__ __launch_bounds__(256) void attn_kernel(
    const bf16* __restrict__ qh, const bf16* __restrict__ kh,
    const bf16* __restrict__ vt, bf16* __restrict__ Obuf)
{
    const int wave = threadIdx.x >> 6;
    const int lane = threadIdx.x & 63;
    const int quad = lane >> 4;
    const int l15  = lane & 15;
    const int qsub  = wave >> 1;   // which 16-row q-tile
    const int jhalf = wave & 1;    // which half of L
    const int bh    = blockIdx.y;
    const int q_base = blockIdx.x * 32 + qsub * 16;

    const bf16* Q = qh + (size_t)bh * L_ * HD_;
    const bf16* K = kh + (size_t)bh * L_ * HD_;
    const bf16* V = vt + (size_t)bh * HD_ * L_;

    __shared__ __align__(16) bf16 Plds[4][16][72];   // 9216 B (+8 pad)
    __shared__ float Cbuf[2][16][64];                // 8192 B combine buffer
    __shared__ float Lbuf[2][16];                    // row-sum combine

    bf16x8 qf[2];
#pragma unroll
    for (int ks = 0; ks < 2; ks++)
        qf[ks] = *(const bf16x8*)(Q + (size_t)(q_base + l15) * HD_ + ks * 32 + quad * 8);

    f32x4 o_acc[4];
    float lsum[4];
#pragma unroll
    for (int nb = 0; nb < 4; nb++) o_acc[nb] = (f32x4){0.f, 0.f, 0.f, 0.f};
#pragma unroll
    for (int r = 0; r < 4; r++) lsum[r] = 0.0f;

    const int j_begin = jhalf * (L_ / 2);
    const int j_end   = j_begin + (L_ / 2);

    for (int j0 = j_begin; j0 < j_end; j0 += 64) {
        // S = Q @ K^T : 16x64, C-layout (row=quad*4+r, col=nb*16+l15)
        f32x4 s_acc[4];
#pragma unroll
        for (int nb = 0; nb < 4; nb++) s_acc[nb] = (f32x4){0.f, 0.f, 0.f, 0.f};
#pragma unroll
        for (int ks = 0; ks < 2; ks++)
#pragma unroll
            for (int nb = 0; nb < 4; nb++) {
                bf16x8 kf = *(const bf16x8*)(K + (size_t)(j0 + nb * 16 + l15) * HD_ + ks * 32 + quad * 8);
                s_acc[nb] = mfma16(qf[ks], kf, s_acc[nb]);
            }

        // P = exp2(S) (scale pre-folded); accumulate per-lane partial sums.
        // No max, no shuffles, no rescale -- shortest possible chain.
#pragma unroll
        for (int r = 0; r < 4; r++) {
            const int prow = quad * 4 + r;
#pragma unroll
            for (int nb = 0; nb < 4; nb++) {
                const float e = __builtin_amdgcn_exp2f(s_acc[nb][r]);
                lsum[r] += e;
                Plds[wave][prow][nb * 16 + l15] = (bf16)e;
            }
        }
        // In-wave write->read ordering for this wave's private LDS region.
        asm volatile("s_waitcnt lgkmcnt(0)" ::: "memory");

        // O += P @ V
#pragma unroll
        for (int ks = 0; ks < 2; ks++) {
            bf16x8 pf = *(const bf16x8*)(&Plds[wave][l15][ks * 32 + quad * 8]);
#pragma unroll
            for (int nb = 0; nb < 4; nb++) {
                bf16x8 vf = *(const bf16x8*)(V + (size_t)(nb * 16 + l15) * L_ + j0 + ks * 32 + quad * 8);
                o_acc[nb] = mfma16(pf, vf, o_acc[nb]);
            }
        }
    }

    // Row-sum: reduce per-lane partials across the 16-lane quad group (once).
#pragma unroll
    for (int r = 0; r < 4; r++) {
        float s = lsum[r];
        s += __shfl_xor(s, 1);
        s += __shfl_xor(s, 2);
        s += __shfl_xor(s, 4);
        s += __shfl_xor(s, 8);
        lsum[r] = s;
    }

    // Combine the two j-halves.
    if (jhalf == 1) {
#pragma unroll
        for (int nb = 0; nb < 4; nb++)
#pragma unroll
            for (int r = 0; r < 4; r++)
                Cbuf[qsub][quad * 4 + r][nb * 16 + l15] = o_acc[nb][r];
        if (l15 == 0)
#pragma unroll
            for (int r = 0; r < 4; r++) Lbuf[qsub][quad * 4 + r] = lsum[r];
    }
    __syncthreads();
    if (jhalf == 0) {
        const int b = bh >> 3, h = bh & 7;
        float inv[4];
#pragma unroll
        for (int r = 0; r < 4; r++)
            inv[r] = 1.0f / (lsum[r] + Lbuf[qsub][quad * 4 + r]);
#pragma unroll
        for (int nb = 0; nb < 4; nb++)
#pragma unroll
            for (int r = 0; r < 4; r++) {
                const int row = q_base + quad * 4 + r;
                const int col = nb * 16 + l15;
                const float ov = (o_acc[nb][r] + Cbuf[qsub][quad * 4 + r][nb * 16 + l15]) * inv[r];
                Obuf[(size_t)(b * L_ + row) * D_ + h * HD_ + col] = (bf16)ov;
            }
    }
}

extern "C" void kernel_launch(void* const* d_in, const int* in_sizes, int n_in,
                              void* d_out, int out_size, void* d_ws, size_t ws_size,
                              hipStream_t stream)
{
    (void)in_sizes; (void)n_in; (void)out_size; (void)ws_size;
    const float* q  = (const float*)d_in[0];
    const float* k  = (const float*)d_in[1];
    const float* v  = (const float*)d_in[2];
    const float* Wq = (const float*)d_in[3];
    const float* bq = (const float*)d_in[4];
    const float* Wk = (const float*)d_in[5];
    const float* bk = (const float*)d_in[6];
    const float* Wv = (const float*)d_in[7];
    const float* bv = (const float*)d_in[8];
    const float* Wo = (const float*)d_in[9];
    const float* bo = (const float*)d_in[10];
    float* out = (float*)d_out;

    char* ws = (char*)d_ws;
    const size_t SZ = (size_t)8 * 1024 * 1024;  // B*H*L*HD * 2B = 8 MB each
    bf16* qh = (bf16*)(ws);
    bf16* kh = (bf16*)(ws + SZ);
    bf16* vt = (bf16*)(ws + 2 * SZ);
    bf16* Ob = (bf16*)(ws + 3 * SZ);

    // exp(s/sqrt(512)) == exp2(s * SCALE_LOG2E); fold into q projection.
    const float SCALE_LOG2E = 0.06377946282349575f;  // (1/sqrt(512))*log2(e)

    dim3 pgrid(M_ / 64, D_ / 128), pblock(512);
    proj_kernel<false, 0><<<pgrid, pblock, 0, stream>>>(q, Wq, bq, qh, SCALE_LOG2E);
    proj_kernel<false, 0><<<pgrid, pblock, 0, stream>>>(k, Wk, bk, kh, 1.0f);
    proj_kernel<false, 1><<<pgrid, pblock, 0, stream>>>(v, Wv, bv, vt, 1.0f);

    attn_kernel<<<dim3(L_ / 32, B_ * H_), dim3(256), 0, stream>>>(qh, kh, vt, Ob);

    proj_kernel<true, 2><<<pgrid, pblock, 0, stream>>>(Ob, Wo, bo, out, 1.0f);
}

// Round 3
// 326.453 us; speedup vs baseline: 1.8752x; 1.8752x over previous
//
#include <hip/hip_runtime.h>
#include <hip/hip_bf16.h>

#define B_  4
#define L_  2048
#define D_  512
#define H_  8
#define HD_ 64
#define M_  (B_ * L_)   // 8192

typedef __bf16 bf16;
typedef __attribute__((ext_vector_type(8)))  __bf16 bf16x8;
typedef __attribute__((ext_vector_type(4)))  __bf16 bf16x4;
typedef __attribute__((ext_vector_type(16))) float  f32x16;

__device__ __forceinline__ f32x16 mfma32(bf16x8 a, bf16x8 b, f32x16 c) {
    return __builtin_amdgcn_mfma_f32_32x32x16_bf16(a, b, c, 0, 0, 0);
}

__device__ __forceinline__ bf16x8 cvt8(float4 x0, float4 x1) {
    bf16x8 t;
    t[0] = (bf16)x0.x; t[1] = (bf16)x0.y; t[2] = (bf16)x0.z; t[3] = (bf16)x0.w;
    t[4] = (bf16)x1.x; t[5] = (bf16)x1.y; t[6] = (bf16)x1.z; t[7] = (bf16)x1.w;
    return t;
}

// C[M,N] = relu(X[M,K] @ W[N,K]^T + b[N]) (*postmul);  M=8192, N=K=512.
// 32x32x16 MFMA. Wave: 32m x 64n. Block 256 thr = 4 waves -> 64m x 128n.
// grid (M/64=128, N/128=4).
// OUT_MODE 0: bf16 head layout [B,H,L,HD].  OUT_MODE 2: fp32 [M,N].
template<bool A_BF16, int OUT_MODE>
__global__ __launch_bounds__(256) void proj_kernel(
    const void* __restrict__ Xv, const float* __restrict__ W,
    const float* __restrict__ bias, void* __restrict__ outv, float postmul)
{
    const int w    = threadIdx.x >> 6;
    const int lane = threadIdx.x & 63;
    const int l31  = lane & 31;
    const int hi   = lane >> 5;
    const int m_base = blockIdx.x * 64  + (w & 1) * 32;
    const int n_base = blockIdx.y * 128 + (w >> 1) * 64;

    const float* Xf = (const float*)Xv;
    const bf16*  Xb = (const bf16*)Xv;

    f32x16 acc[2];
#pragma unroll
    for (int nf = 0; nf < 2; nf++)
#pragma unroll
        for (int r = 0; r < 16; r++) acc[nf][r] = 0.0f;

    auto loadA = [&](int k0) -> bf16x8 {
        const size_t off = (size_t)(m_base + l31) * D_ + k0 + hi * 8;
        if (A_BF16) return *(const bf16x8*)(Xb + off);
        const float4* p = (const float4*)(Xf + off);
        return cvt8(p[0], p[1]);
    };
    auto loadB = [&](int nf, int k0) -> bf16x8 {
        const float4* p = (const float4*)(W + (size_t)(n_base + nf * 32 + l31) * D_ + k0 + hi * 8);
        return cvt8(p[0], p[1]);
    };

    bf16x8 aC = loadA(0), bC0 = loadB(0, 0), bC1 = loadB(1, 0);
    for (int ks = 0; ks < 32; ks++) {
        const int kn = (ks < 31 ? ks + 1 : 31) * 16;
        bf16x8 aN = loadA(kn);
        bf16x8 bN0 = loadB(0, kn), bN1 = loadB(1, kn);
        acc[0] = mfma32(aC, bC0, acc[0]);
        acc[1] = mfma32(aC, bC1, acc[1]);
        aC = aN; bC0 = bN0; bC1 = bN1;
    }

#pragma unroll
    for (int nf = 0; nf < 2; nf++) {
        const int col = n_base + nf * 32 + l31;
        const float bn = bias[col];
#pragma unroll
        for (int r = 0; r < 16; r++) {
            const int row = m_base + (r & 3) + 8 * (r >> 2) + 4 * hi;
            float v = fmaxf(acc[nf][r] + bn, 0.0f);
            if (OUT_MODE == 2) {
                ((float*)outv)[(size_t)row * D_ + col] = v;
            } else {
                v *= postmul;
                const int b = row >> 11, l = row & (L_ - 1);
                const int h = col >> 6,  hd = col & (HD_ - 1);
                ((bf16*)outv)[((size_t)(b * H_ + h) * L_ + l) * HD_ + hd] = (bf16)v;
            }
        }
    }
}

// vh [BH][L][HD] -> vt [BH][HD][L].  grid (L/64, BH), block 256.
__global__ __launch_bounds__(256) void transpose_v(
    const bf16* __restrict__ vh, bf16* __restrict__ vt)
{
    __shared__ __align__(16) bf16 tile[64][72];  // stride 144 B (16B-aligned rows)
    const int bh = blockIdx.y, l0 = blockIdx.x * 64;
    const bf16* src = vh + (size_t)bh * L_ * HD_;
    bf16*       dst = vt + (size_t)bh * HD_ * L_;
    const int x = threadIdx.x;
#pragma unroll
    for (int m = 0; m < 2; m++) {
        const int s = m * 256 + x;
        const int l = s >> 3, c = s & 7;
        *(bf16x8*)(&tile[l][c * 8]) = *(const bf16x8*)(src + (size_t)(l0 + l) * HD_ + c * 8);
    }
    __syncthreads();
#pragma unroll
    for (int m = 0; m < 2; m++) {
        const int s = m * 256 + x;
        const int hd = s >> 3, lc = s & 7;
        bf16x8 v;
#pragma unroll
        for (int e = 0; e < 8; e++) v[e] = tile[lc * 8 + e][hd];
        *(bf16x8*)(dst + (size_t)hd * L_ + l0 + lc * 8) = v;
    }
}

// Flash attention, max-free (post-ReLU q,k => scores >= 0; exp2 cannot
// overflow fp32; row-sum deferred).  qh pre-scaled by (1/sqrt(512))*log2(e).
// Block: 4 waves x 32 q-rows = 128 q.  grid (L/128=16, BH=32).
// Per j-tile (64): K,V tiles staged to LDS in FRAGMENT-MAJOR order
// (lane-contiguous -> conflict-free b128), register-prefetched one tile ahead.
// S^T = K @ Q^T via MFMA(A=K,B=Q): C-layout gives 4 consecutive j per 4 regs
// at fixed q=lane&31 -> packed b64 P-writes in PV A-operand layout.
__global__ __launch_bounds__(256, 2) void attn_kernel(
    const bf16* __restrict__ qh, const bf16* __restrict__ kh,
    const bf16* __restrict__ vt, bf16* __restrict__ Obuf)
{
    const int w    = threadIdx.x >> 6;
    const int lane = threadIdx.x & 63;
    const int l31  = lane & 31;
    const int hi   = lane >> 5;
    const int bh   = blockIdx.y;
    const int q_base = blockIdx.x * 128 + w * 32;

    const bf16* Q = qh + (size_t)bh * L_ * HD_;
    const bf16* K = kh + (size_t)bh * L_ * HD_;
    const bf16* V = vt + (size_t)bh * HD_ * L_;

    // frag-major: block f (0..7), lane, 16 B.  f = ks*2 + jt (K) / ksj*2 + nbh (V)
    __shared__ __align__(16) bf16 Kbuf[8][64][8];   // 8 KB
    __shared__ __align__(16) bf16 Vbuf[8][64][8];   // 8 KB
    __shared__ __align__(16) bf16 Pl[4][32][68];    // per-wave P, row q, stride 136 B
    __shared__ float Lw[4][32];

    // Q fragments (B-operand): n = q = lane&31, k = ks*16 + hi*8 + j
    bf16x8 qf[4];
#pragma unroll
    for (int ks = 0; ks < 4; ks++)
        qf[ks] = *(const bf16x8*)(Q + (size_t)(q_base + l31) * HD_ + ks * 16 + hi * 8);

    f32x16 o0, o1;
#pragma unroll
    for (int r = 0; r < 16; r++) { o0[r] = 0.0f; o1[r] = 0.0f; }
    float lsum = 0.0f;

    const int f1 = w, f2 = w + 4;
    auto kga = [&](int f, int j0) {
        return K + (size_t)(j0 + (f & 1) * 32 + l31) * HD_ + (f >> 1) * 16 + hi * 8;
    };
    auto vga = [&](int f, int j0) {
        return V + (size_t)((f & 1) * 32 + l31) * L_ + j0 + (f >> 1) * 16 + hi * 8;
    };

    bf16x8 kr0 = *(const bf16x8*)kga(f1, 0), kr1 = *(const bf16x8*)kga(f2, 0);
    bf16x8 vr0 = *(const bf16x8*)vga(f1, 0), vr1 = *(const bf16x8*)vga(f2, 0);

    for (int j0 = 0; j0 < L_; j0 += 64) {
        __syncthreads();                 // previous tile's LDS reads done
        *(bf16x8*)(&Kbuf[f1][lane][0]) = kr0;
        *(bf16x8*)(&Kbuf[f2][lane][0]) = kr1;
        *(bf16x8*)(&Vbuf[f1][lane][0]) = vr0;
        *(bf16x8*)(&Vbuf[f2][lane][0]) = vr1;
        const int jn = (j0 + 64 < L_) ? j0 + 64 : j0;   // last prefetch redundant
        kr0 = *(const bf16x8*)kga(f1, jn);
        kr1 = *(const bf16x8*)kga(f2, jn);
        vr0 = *(const bf16x8*)vga(f1, jn);
        vr1 = *(const bf16x8*)vga(f2, jn);
        __syncthreads();                 // staged tile visible

        // S^T: D[m=j][n=q], two 32-j sub-tiles
        f32x16 s0, s1;
#pragma unroll
        for (int r = 0; r < 16; r++) { s0[r] = 0.0f; s1[r] = 0.0f; }
#pragma unroll
        for (int ks = 0; ks < 4; ks++) {
            s0 = mfma32(*(const bf16x8*)(&Kbuf[ks * 2 + 0][lane][0]), qf[ks], s0);
            s1 = mfma32(*(const bf16x8*)(&Kbuf[ks * 2 + 1][lane][0]), qf[ks], s1);
        }

        // P = exp2(S^T); lane's 4 consecutive regs = 4 consecutive j at q=l31.
#pragma unroll
        for (int jt = 0; jt < 2; jt++) {
            const f32x16& s = jt ? s1 : s0;
#pragma unroll
            for (int g = 0; g < 4; g++) {
                const float e0 = __builtin_amdgcn_exp2f(s[g * 4 + 0]);
                const float e1 = __builtin_amdgcn_exp2f(s[g * 4 + 1]);
                const float e2 = __builtin_amdgcn_exp2f(s[g * 4 + 2]);
                const float e3 = __builtin_amdgcn_exp2f(s[g * 4 + 3]);
                lsum += (e0 + e1) + (e2 + e3);
                bf16x4 pv;
                pv[0] = (bf16)e0; pv[1] = (bf16)e1; pv[2] = (bf16)e2; pv[3] = (bf16)e3;
                *(bf16x4*)(&Pl[w][l31][jt * 32 + g * 8 + hi * 4]) = pv;
            }
        }
        asm volatile("s_waitcnt lgkmcnt(0)" ::: "memory");  // in-wave P visibility

        // O += P @ V: A[m=q][k=j] from Pl, B[n=hd][k=j] frag-major from Vbuf
#pragma unroll
        for (int ksj = 0; ksj < 4; ksj++) {
            const bf16x4 pa = *(const bf16x4*)(&Pl[w][l31][ksj * 16 + hi * 8]);
            const bf16x4 pb = *(const bf16x4*)(&Pl[w][l31][ksj * 16 + hi * 8 + 4]);
            bf16x8 pf;
#pragma unroll
            for (int e = 0; e < 4; e++) { pf[e] = pa[e]; pf[e + 4] = pb[e]; }
            o0 = mfma32(pf, *(const bf16x8*)(&Vbuf[ksj * 2 + 0][lane][0]), o0);
            o1 = mfma32(pf, *(const bf16x8*)(&Vbuf[ksj * 2 + 1][lane][0]), o1);
        }
    }

    // Combine the two half-lane partial sums; broadcast per-q row sums.
    lsum += __shfl_xor(lsum, 32);
    if (lane < 32) Lw[w][lane] = lsum;
    asm volatile("s_waitcnt lgkmcnt(0)" ::: "memory");

    const int b = bh >> 3, h = bh & 7;
#pragma unroll
    for (int r = 0; r < 16; r++) {
        const int q_r = (r & 3) + 8 * (r >> 2) + 4 * hi;
        const float inv = 1.0f / Lw[w][q_r];
        const size_t base = (size_t)(b * L_ + q_base + q_r) * D_ + h * HD_;
        Obuf[base + l31]      = (bf16)(o0[r] * inv);
        Obuf[base + 32 + l31] = (bf16)(o1[r] * inv);
    }
}

extern "C" void kernel_launch(void* const* d_in, const int* in_sizes, int n_in,
                              void* d_out, int out_size, void* d_ws, size_t ws_size,
                              hipStream_t stream)
{
    (void)in_sizes; (void)n_in; (void)out_size; (void)ws_size;
    const float* q  = (const float*)d_in[0];
    const float* k  = (const float*)d_in[1];
    const float* v  = (const float*)d_in[2];
    const float* Wq = (const float*)d_in[3];
    const float* bq = (const float*)d_in[4];
    const float* Wk = (const float*)d_in[5];
    const float* bk = (const float*)d_in[6];
    const float* Wv = (const float*)d_in[7];
    const float* bv = (const float*)d_in[8];
    const float* Wo = (const float*)d_in[9];
    const float* bo = (const float*)d_in[10];
    float* out = (float*)d_out;

    char* ws = (char*)d_ws;
    const size_t SZ = (size_t)8 * 1024 * 1024;  // 8 MB per [B,H,L,HD] bf16 buffer
    bf16* qh = (bf16*)(ws);
    bf16* kh = (bf16*)(ws + SZ);
    bf16* vh = (bf16*)(ws + 2 * SZ);   // row-major V heads; dead after transpose
    bf16* vt = (bf16*)(ws + 3 * SZ);   // transposed V
    bf16* Ob = vh;                     // alias: attn output reuses vh

    // exp(s/sqrt(512)) == exp2(s * SCALE_LOG2E); folded into q projection.
    const float SCALE_LOG2E = 0.06377946282349575f;

    dim3 pgrid(M_ / 64, D_ / 128), pblock(256);
    proj_kernel<false, 0><<<pgrid, pblock, 0, stream>>>(q, Wq, bq, qh, SCALE_LOG2E);
    proj_kernel<false, 0><<<pgrid, pblock, 0, stream>>>(k, Wk, bk, kh, 1.0f);
    proj_kernel<false, 0><<<pgrid, pblock, 0, stream>>>(v, Wv, bv, vh, 1.0f);

    transpose_v<<<dim3(L_ / 64, B_ * H_), pblock, 0, stream>>>(vh, vt);

    attn_kernel<<<dim3(L_ / 128, B_ * H_), pblock, 0, stream>>>(qh, kh, vt, Ob);

    proj_kernel<true, 2><<<pgrid, pblock, 0, stream>>>(Ob, Wo, bo, out, 1.0f);
}

// Round 5
// 274.630 us; speedup vs baseline: 2.2291x; 1.1887x over previous
//
#include <hip/hip_runtime.h>
#include <hip/hip_bf16.h>

#define B_  4
#define L_  2048
#define D_  512
#define H_  8
#define HD_ 64
#define M_  (B_ * L_)   // 8192

typedef __bf16 bf16;
typedef __attribute__((ext_vector_type(8)))  __bf16 bf16x8;
typedef __attribute__((ext_vector_type(16))) float  f32x16;

__device__ __forceinline__ f32x16 mfma32(bf16x8 a, bf16x8 b, f32x16 c) {
    return __builtin_amdgcn_mfma_f32_32x32x16_bf16(a, b, c, 0, 0, 0);
}

__device__ __forceinline__ bf16x8 cvt8(float4 x0, float4 x1) {
    bf16x8 t;
    t[0] = (bf16)x0.x; t[1] = (bf16)x0.y; t[2] = (bf16)x0.z; t[3] = (bf16)x0.w;
    t[4] = (bf16)x1.x; t[5] = (bf16)x1.y; t[6] = (bf16)x1.z; t[7] = (bf16)x1.w;
    return t;
}

// C[M,N] = relu(X[M,K] @ W[N,K]^T + b[N]) (*postmul);  M=8192, N=K=512.
// Frag-major LDS-staged GEMM: block 256 thr / 4 waves, tile 128m x 64n,
// k-step 64, fp32->bf16 conversion once per block at staging time,
// register prefetch one k-step ahead. grid (64, 8) = 512 blocks (2/CU).
// OUT_MODE 0: bf16 head layout [B,H,L,HD].  OUT_MODE 2: fp32 [M,N].
template<bool A_BF16, int OUT_MODE>
__global__ __launch_bounds__(256, 2) void proj_kernel(
    const void* __restrict__ Xv, const float* __restrict__ W,
    const float* __restrict__ bias, void* __restrict__ outv, float postmul)
{
    const int w    = threadIdx.x >> 6;
    const int lane = threadIdx.x & 63;
    const int l31  = lane & 31;
    const int hi   = lane >> 5;
    const int m0 = blockIdx.x * 128;
    const int n0 = blockIdx.y * 64;
    const int mh = w & 1;    // wave m-half (frag quarters 2mh, 2mh+1)
    const int nh = w >> 1;   // wave n-half (32 cols)

    // frag-major: [f][lane][8].  A f = ks*4+mq (16 KB), B f = ks*2+ns (8 KB).
    __shared__ __align__(16) bf16 Abuf[16][64][8];
    __shared__ __align__(16) bf16 Bbuf[8][64][8];

    const float* Xf = (const float*)Xv;
    const bf16*  Xb = (const bf16*)Xv;

    f32x16 acc[2];
#pragma unroll
    for (int mi = 0; mi < 2; mi++)
#pragma unroll
        for (int r = 0; r < 16; r++) acc[mi][r] = 0.0f;

    auto ldA = [&](int f, int k0) -> bf16x8 {   // f: ks=f>>2, mq=f&3
        const int m = (f & 3) * 32 + l31;
        const int k = k0 + (f >> 2) * 16 + hi * 8;
        const size_t off = (size_t)(m0 + m) * D_ + k;
        if (A_BF16) return *(const bf16x8*)(Xb + off);
        const float4* p = (const float4*)(Xf + off);
        return cvt8(p[0], p[1]);
    };
    auto ldB = [&](int f, int k0) -> bf16x8 {   // f: ks=f>>1, ns=f&1
        const int n = (f & 1) * 32 + l31;
        const int k = k0 + (f >> 1) * 16 + hi * 8;
        const float4* p = (const float4*)(W + (size_t)(n0 + n) * D_ + k);
        return cvt8(p[0], p[1]);
    };

    bf16x8 ra[4], rb[2];
#pragma unroll
    for (int i = 0; i < 4; i++) ra[i] = ldA(w * 4 + i, 0);
#pragma unroll
    for (int i = 0; i < 2; i++) rb[i] = ldB(w * 2 + i, 0);

    for (int it = 0; it < 8; it++) {
        __syncthreads();   // previous iter's LDS reads complete
#pragma unroll
        for (int i = 0; i < 4; i++) *(bf16x8*)(&Abuf[w * 4 + i][lane][0]) = ra[i];
#pragma unroll
        for (int i = 0; i < 2; i++) *(bf16x8*)(&Bbuf[w * 2 + i][lane][0]) = rb[i];
        __syncthreads();   // staged tile visible
        const int kn = (it < 7 ? it + 1 : 7) * 64;   // last prefetch redundant
#pragma unroll
        for (int i = 0; i < 4; i++) ra[i] = ldA(w * 4 + i, kn);
#pragma unroll
        for (int i = 0; i < 2; i++) rb[i] = ldB(w * 2 + i, kn);
#pragma unroll
        for (int ks = 0; ks < 4; ks++) {
            const bf16x8 bfr = *(const bf16x8*)(&Bbuf[ks * 2 + nh][lane][0]);
#pragma unroll
            for (int mi = 0; mi < 2; mi++) {
                const bf16x8 afr = *(const bf16x8*)(&Abuf[ks * 4 + mh * 2 + mi][lane][0]);
                acc[mi] = mfma32(afr, bfr, acc[mi]);
            }
        }
    }

    const int col = n0 + nh * 32 + l31;
    const float bn = bias[col];
#pragma unroll
    for (int mi = 0; mi < 2; mi++)
#pragma unroll
        for (int r = 0; r < 16; r++) {
            const int row = m0 + (mh * 2 + mi) * 32 + (r & 3) + 8 * (r >> 2) + 4 * hi;
            float v = fmaxf(acc[mi][r] + bn, 0.0f);
            if (OUT_MODE == 2) {
                ((float*)outv)[(size_t)row * D_ + col] = v;
            } else {
                v *= postmul;
                const int b = row >> 11, l = row & (L_ - 1);
                const int h = col >> 6,  hd = col & (HD_ - 1);
                ((bf16*)outv)[((size_t)(b * H_ + h) * L_ + l) * HD_ + hd] = (bf16)v;
            }
        }
}

// vh [BH][L][HD] -> vt [BH][HD][L'] where within each 16-j group the j index
// is PI-swizzled (swap bits 2<->3).  PI is applied identically to the P
// operand's natural register order in attn, so the PV MFMA contraction is
// invariant.  grid (L/64, BH), block 256.
__global__ __launch_bounds__(256) void transpose_v(
    const bf16* __restrict__ vh, bf16* __restrict__ vt)
{
    __shared__ __align__(16) bf16 tile[64][72];
    const int bh = blockIdx.y, l0 = blockIdx.x * 64;
    const bf16* src = vh + (size_t)bh * L_ * HD_;
    bf16*       dst = vt + (size_t)bh * HD_ * L_;
    const int x = threadIdx.x;
#pragma unroll
    for (int m = 0; m < 2; m++) {
        const int s = m * 256 + x;
        const int l = s >> 3, c = s & 7;
        *(bf16x8*)(&tile[l][c * 8]) = *(const bf16x8*)(src + (size_t)(l0 + l) * HD_ + c * 8);
    }
    __syncthreads();
#pragma unroll
    for (int m = 0; m < 2; m++) {
        const int s = m * 256 + x;
        const int hd = s >> 3, lc = s & 7;
        bf16x8 v;
#pragma unroll
        for (int e = 0; e < 8; e++) {
            const int p = lc * 8 + e;
            const int t = p & 15;
            const int tp = (t & 3) | ((t & 4) << 1) | ((t & 8) >> 1);  // swap bits 2,3
            v[e] = tile[(p & 48) | tp][hd];
        }
        *(bf16x8*)(dst + (size_t)hd * L_ + l0 + lc * 8) = v;
    }
}

// Flash attention, max-free (post-ReLU q,k => scores >= 0, exp2 can't
// overflow fp32, row-sum deferred).  qh pre-scaled by (1/sqrt(512))*log2(e).
// Block: 2 waves x 64q = 128q.  grid (L/128=16, BH=32) = 512 blocks (2/CU).
// Per 64-j tile: K,V staged frag-major (conflict-free b128), register
// prefetch one tile ahead.  S^T = K @ Q^T in C-layout; P enters the PV MFMA
// in NATURAL register order -- valid because V's j-index was PI-swizzled at
// transpose time (same permutation on both operands' k => product unchanged).
__global__ __launch_bounds__(128, 2) void attn_kernel(
    const bf16* __restrict__ qh, const bf16* __restrict__ kh,
    const bf16* __restrict__ vt, bf16* __restrict__ Obuf)
{
    const int w    = threadIdx.x >> 6;   // 0..1
    const int lane = threadIdx.x & 63;
    const int l31  = lane & 31;
    const int hi   = lane >> 5;
    const int bh   = blockIdx.y;
    const int qb   = blockIdx.x * 128 + w * 64;

    const bf16* Q = qh + (size_t)bh * L_ * HD_;
    const bf16* K = kh + (size_t)bh * L_ * HD_;
    const bf16* V = vt + (size_t)bh * HD_ * L_;   // PI-swizzled j

    __shared__ __align__(16) bf16 Kbuf[8][64][8];   // f = ks*2 + jt
    __shared__ __align__(16) bf16 Vbuf[8][64][8];   // f = ksj*2 + hdf
    __shared__ float Lw[2][2][32];

    // Q fragments (B-operand): n=q=l31 (+32*qi), k = ks*16 + hi*8 + e
    bf16x8 qf[2][4];
#pragma unroll
    for (int qi = 0; qi < 2; qi++)
#pragma unroll
        for (int ks = 0; ks < 4; ks++)
            qf[qi][ks] = *(const bf16x8*)(Q + (size_t)(qb + qi * 32 + l31) * HD_ + ks * 16 + hi * 8);

    f32x16 o[2][2];
#pragma unroll
    for (int qi = 0; qi < 2; qi++)
#pragma unroll
        for (int hf = 0; hf < 2; hf++)
#pragma unroll
            for (int r = 0; r < 16; r++) o[qi][hf][r] = 0.0f;
    float lsum[2] = {0.0f, 0.0f};

    auto kga = [&](int f, int j0) {   // K f: ks=f>>1, jt=f&1
        return K + (size_t)(j0 + (f & 1) * 32 + l31) * HD_ + (f >> 1) * 16 + hi * 8;
    };
    auto vga = [&](int f, int j0) {   // V f: ksj=f>>1, hdf=f&1
        return V + (size_t)((f & 1) * 32 + l31) * L_ + j0 + (f >> 1) * 16 + hi * 8;
    };

    bf16x8 kr[4], vr[4];
#pragma unroll
    for (int i = 0; i < 4; i++) {
        kr[i] = *(const bf16x8*)kga(w * 4 + i, 0);
        vr[i] = *(const bf16x8*)vga(w * 4 + i, 0);
    }

    for (int j0 = 0; j0 < L_; j0 += 64) {
        __syncthreads();
#pragma unroll
        for (int i = 0; i < 4; i++) {
            *(bf16x8*)(&Kbuf[w * 4 + i][lane][0]) = kr[i];
            *(bf16x8*)(&Vbuf[w * 4 + i][lane][0]) = vr[i];
        }
        __syncthreads();
        const int jn = (j0 + 64 < L_) ? j0 + 64 : j0;   // last prefetch redundant
#pragma unroll
        for (int i = 0; i < 4; i++) {
            kr[i] = *(const bf16x8*)kga(w * 4 + i, jn);
            vr[i] = *(const bf16x8*)vga(w * 4 + i, jn);
        }

        // S^T[j][q]: K-frag (A) read once per (ks,jt), 2 MFMAs each (qi).
        f32x16 s[2][2];
#pragma unroll
        for (int jt = 0; jt < 2; jt++)
#pragma unroll
            for (int qi = 0; qi < 2; qi++)
#pragma unroll
                for (int r = 0; r < 16; r++) s[jt][qi][r] = 0.0f;
#pragma unroll
        for (int ks = 0; ks < 4; ks++)
#pragma unroll
            for (int jt = 0; jt < 2; jt++) {
                const bf16x8 kfr = *(const bf16x8*)(&Kbuf[ks * 2 + jt][lane][0]);
#pragma unroll
                for (int qi = 0; qi < 2; qi++)
                    s[jt][qi] = mfma32(kfr, qf[qi][ks], s[jt][qi]);
            }

        // exp2 in place + per-lane row-sum partials (lane owns q=l31; the two
        // hi halves hold disjoint j subsets).
#pragma unroll
        for (int jt = 0; jt < 2; jt++)
#pragma unroll
            for (int qi = 0; qi < 2; qi++)
#pragma unroll
                for (int r = 0; r < 16; r++) {
                    const float e = __builtin_amdgcn_exp2f(s[jt][qi][r]);
                    s[jt][qi][r] = e;
                    lsum[qi] += e;
                }

        // O += P @ V.  P A-frag = natural-order regs (PI-matched with V).
#pragma unroll
        for (int ksj = 0; ksj < 4; ksj++) {
            bf16x8 vfr[2];
#pragma unroll
            for (int hf = 0; hf < 2; hf++)
                vfr[hf] = *(const bf16x8*)(&Vbuf[ksj * 2 + hf][lane][0]);
#pragma unroll
            for (int qi = 0; qi < 2; qi++) {
                const f32x16& sv = s[ksj >> 1][qi];
                const int b8 = (ksj & 1) * 8;
                bf16x8 pf;
#pragma unroll
                for (int u = 0; u < 8; u++) pf[u] = (bf16)sv[b8 + u];
#pragma unroll
                for (int hf = 0; hf < 2; hf++)
                    o[qi][hf] = mfma32(pf, vfr[hf], o[qi][hf]);
            }
        }
    }

    // Finish row sums (hi halves hold disjoint j), broadcast via LDS (in-wave).
#pragma unroll
    for (int qi = 0; qi < 2; qi++) {
        lsum[qi] += __shfl_xor(lsum[qi], 32);
        if (hi == 0) Lw[w][qi][l31] = lsum[qi];
    }
    asm volatile("s_waitcnt lgkmcnt(0)" ::: "memory");

    const int b = bh >> 3, h = bh & 7;
#pragma unroll
    for (int qi = 0; qi < 2; qi++)
#pragma unroll
        for (int r = 0; r < 16; r++) {
            const int rl = (r & 3) + 8 * (r >> 2) + 4 * hi;
            const float inv = 1.0f / Lw[w][qi][rl];
            const size_t base = (size_t)(b * L_ + qb + qi * 32 + rl) * D_ + h * HD_;
#pragma unroll
            for (int hf = 0; hf < 2; hf++)
                Obuf[base + hf * 32 + l31] = (bf16)(o[qi][hf][r] * inv);
        }
}

extern "C" void kernel_launch(void* const* d_in, const int* in_sizes, int n_in,
                              void* d_out, int out_size, void* d_ws, size_t ws_size,
                              hipStream_t stream)
{
    (void)in_sizes; (void)n_in; (void)out_size; (void)ws_size;
    const float* q  = (const float*)d_in[0];
    const float* k  = (const float*)d_in[1];
    const float* v  = (const float*)d_in[2];
    const float* Wq = (const float*)d_in[3];
    const float* bq = (const float*)d_in[4];
    const float* Wk = (const float*)d_in[5];
    const float* bk = (const float*)d_in[6];
    const float* Wv = (const float*)d_in[7];
    const float* bv = (const float*)d_in[8];
    const float* Wo = (const float*)d_in[9];
    const float* bo = (const float*)d_in[10];
    float* out = (float*)d_out;

    char* ws = (char*)d_ws;
    const size_t SZ = (size_t)8 * 1024 * 1024;
    bf16* qh = (bf16*)(ws);
    bf16* kh = (bf16*)(ws + SZ);
    bf16* vh = (bf16*)(ws + 2 * SZ);   // row-major V heads; dead after transpose
    bf16* vt = (bf16*)(ws + 3 * SZ);   // PI-swizzled transposed V
    bf16* Ob = vh;                     // attn output reuses vh

    const float SCALE_LOG2E = 0.06377946282349575f;  // (1/sqrt(512))*log2(e)

    dim3 pgrid(M_ / 128, D_ / 64), pblock(256);
    proj_kernel<false, 0><<<pgrid, pblock, 0, stream>>>(q, Wq, bq, qh, SCALE_LOG2E);
    proj_kernel<false, 0><<<pgrid, pblock, 0, stream>>>(k, Wk, bk, kh, 1.0f);
    proj_kernel<false, 0><<<pgrid, pblock, 0, stream>>>(v, Wv, bv, vh, 1.0f);

    transpose_v<<<dim3(L_ / 64, B_ * H_), pblock, 0, stream>>>(vh, vt);

    attn_kernel<<<dim3(L_ / 128, B_ * H_), dim3(128), 0, stream>>>(qh, kh, vt, Ob);

    proj_kernel<true, 2><<<pgrid, pblock, 0, stream>>>(Ob, Wo, bo, out, 1.0f);
}

// Round 6
// 215.627 us; speedup vs baseline: 2.8390x; 1.2736x over previous
//
#include <hip/hip_runtime.h>
#include <hip/hip_bf16.h>

#define B_  4
#define L_  2048
#define D_  512
#define H_  8
#define HD_ 64
#define M_  (B_ * L_)   // 8192

typedef __bf16 bf16;
typedef __attribute__((ext_vector_type(8)))  __bf16 bf16x8;
typedef __attribute__((ext_vector_type(4)))  __bf16 bf16x4;
typedef __attribute__((ext_vector_type(16))) float  f32x16;

__device__ __forceinline__ f32x16 mfma32(bf16x8 a, bf16x8 b, f32x16 c) {
    return __builtin_amdgcn_mfma_f32_32x32x16_bf16(a, b, c, 0, 0, 0);
}

// ---- pack: src fp32 [R][512] -> dst bf16 panels [64][R][8] ----
// dst[kp][m][e] = (bf16)src[m][kp*8+e].  Coalesced loads AND stores via LDS.
__device__ __forceinline__ void pack_body(const float* __restrict__ src,
                                          bf16* __restrict__ dst, int R,
                                          int m0, int k0)
{
    __shared__ __align__(16) bf16 tile[64][76];   // stride 152 B (8B-aligned rows)
    const int t = threadIdx.x;
#pragma unroll
    for (int rep = 0; rep < 4; rep++) {
        const int idx = rep * 256 + t;
        const int r = idx >> 4, c4 = idx & 15;       // 4 consecutive fp32 per thread
        const float4 f = *(const float4*)(src + (size_t)(m0 + r) * 512 + k0 + c4 * 4);
        bf16x4 v; v[0] = (bf16)f.x; v[1] = (bf16)f.y; v[2] = (bf16)f.z; v[3] = (bf16)f.w;
        *(bf16x4*)(&tile[r][c4 * 4]) = v;
    }
    __syncthreads();
#pragma unroll
    for (int rep = 0; rep < 2; rep++) {
        const int s = rep * 256 + t;
        const int ml = s & 63, kpl = s >> 6;         // ml fast -> coalesced store
        const bf16x4 lo = *(const bf16x4*)(&tile[ml][kpl * 8]);
        const bf16x4 hi4 = *(const bf16x4*)(&tile[ml][kpl * 8 + 4]);
        bf16x8 v;
#pragma unroll
        for (int e = 0; e < 4; e++) { v[e] = lo[e]; v[e + 4] = hi4[e]; }
        *(bf16x8*)(dst + ((size_t)(k0 / 8 + kpl) * R + m0 + ml) * 8) = v;
    }
}

// grid (R/64, 8), block 256
__global__ __launch_bounds__(256) void pack_x(const float* __restrict__ src,
                                              bf16* __restrict__ dst, int R)
{
    pack_body(src, dst, R, blockIdx.x * 64, blockIdx.y * 64);
}

// grid (8, 8, 4), block 256 — packs all four 512x512 weight matrices
__global__ __launch_bounds__(256) void pack_w(const float* __restrict__ w0,
                                              const float* __restrict__ w1,
                                              const float* __restrict__ w2,
                                              const float* __restrict__ w3,
                                              bf16* __restrict__ dst)
{
    const float* src = blockIdx.z == 0 ? w0 : blockIdx.z == 1 ? w1
                     : blockIdx.z == 2 ? w2 : w3;
    bf16* d = dst + (size_t)blockIdx.z * 64 * 512 * 8;
    pack_body(src, d, 512, blockIdx.x * 64, blockIdx.y * 64);
}

// ---- projection: C[M,N] = relu(Xp @ Wp^T + b) (*postmul) ----
// Inputs in panel layout: Xp [64][M_][8], Wp [64][512][8] (both bf16).
// Round-5-verified staged structure; only the global source addressing changed
// (now lane-contiguous 512B runs).  Block 256/4 waves, tile 128m x 64n, k-step
// 64, register prefetch one k-step ahead.  grid (64, 8) = 512 blocks.
// OUT_MODE 0: bf16 head layout [B,H,L,HD]
// OUT_MODE 1: bf16 K-panels  [BH][8][L][8]
// OUT_MODE 2: fp32 row-major [M,N] (final output)
template<int OUT_MODE>
__global__ __launch_bounds__(256, 2) void proj_kernel(
    const bf16* __restrict__ Xp, const bf16* __restrict__ Wp,
    const float* __restrict__ bias, void* __restrict__ outv, float postmul)
{
    const int w    = threadIdx.x >> 6;
    const int lane = threadIdx.x & 63;
    const int l31  = lane & 31;
    const int hi   = lane >> 5;
    const int m0 = blockIdx.x * 128;
    const int n0 = blockIdx.y * 64;
    const int mh = w & 1;    // wave m-half (frag quarters 2mh, 2mh+1)
    const int nh = w >> 1;   // wave n-half (32 cols)

    // frag-major LDS: [f][lane][8].  A f = ks*4+mq, B f = ks*2+ns.
    __shared__ __align__(16) bf16 Abuf[16][64][8];
    __shared__ __align__(16) bf16 Bbuf[8][64][8];

    f32x16 acc[2];
#pragma unroll
    for (int mi = 0; mi < 2; mi++)
#pragma unroll
        for (int r = 0; r < 16; r++) acc[mi][r] = 0.0f;

    auto ldA = [&](int f, int k0) -> bf16x8 {   // f: ks=f>>2, mq=f&3
        return *(const bf16x8*)(Xp + ((size_t)((k0 >> 3) + (f >> 2) * 2 + hi) * M_
                                      + m0 + (f & 3) * 32 + l31) * 8);
    };
    auto ldB = [&](int f, int k0) -> bf16x8 {   // f: ks=f>>1, ns=f&1
        return *(const bf16x8*)(Wp + ((size_t)((k0 >> 3) + (f >> 1) * 2 + hi) * 512
                                      + n0 + (f & 1) * 32 + l31) * 8);
    };

    bf16x8 ra[4], rb[2];
#pragma unroll
    for (int i = 0; i < 4; i++) ra[i] = ldA(w * 4 + i, 0);
#pragma unroll
    for (int i = 0; i < 2; i++) rb[i] = ldB(w * 2 + i, 0);

    for (int it = 0; it < 8; it++) {
        __syncthreads();
#pragma unroll
        for (int i = 0; i < 4; i++) *(bf16x8*)(&Abuf[w * 4 + i][lane][0]) = ra[i];
#pragma unroll
        for (int i = 0; i < 2; i++) *(bf16x8*)(&Bbuf[w * 2 + i][lane][0]) = rb[i];
        __syncthreads();
        const int kn = (it < 7 ? it + 1 : 7) * 64;
#pragma unroll
        for (int i = 0; i < 4; i++) ra[i] = ldA(w * 4 + i, kn);
#pragma unroll
        for (int i = 0; i < 2; i++) rb[i] = ldB(w * 2 + i, kn);
#pragma unroll
        for (int ks = 0; ks < 4; ks++) {
            const bf16x8 bfr = *(const bf16x8*)(&Bbuf[ks * 2 + nh][lane][0]);
#pragma unroll
            for (int mi = 0; mi < 2; mi++) {
                const bf16x8 afr = *(const bf16x8*)(&Abuf[ks * 4 + mh * 2 + mi][lane][0]);
                acc[mi] = mfma32(afr, bfr, acc[mi]);
            }
        }
    }

    const int col = n0 + nh * 32 + l31;
    const float bn = bias[col];
#pragma unroll
    for (int mi = 0; mi < 2; mi++)
#pragma unroll
        for (int r = 0; r < 16; r++) {
            const int row = m0 + (mh * 2 + mi) * 32 + (r & 3) + 8 * (r >> 2) + 4 * hi;
            float v = fmaxf(acc[mi][r] + bn, 0.0f);
            if (OUT_MODE == 2) {
                ((float*)outv)[(size_t)row * D_ + col] = v;
            } else {
                v *= postmul;
                const int b = row >> 11, l = row & (L_ - 1);
                const int h = col >> 6,  hd = col & (HD_ - 1);
                size_t idx;
                if (OUT_MODE == 0)
                    idx = ((size_t)(b * H_ + h) * L_ + l) * HD_ + hd;
                else  // K panels [bh][hd>>3][l][hd&7]
                    idx = (((size_t)(b * H_ + h) * 8 + (hd >> 3)) * L_ + l) * 8 + (hd & 7);
                ((bf16*)outv)[idx] = (bf16)v;
            }
        }
}

// vh [BH][L][HD] -> Vp [BH][256][64][8]: Vp[bh][jq][hd][e] = vh[bh][swz(jq*8+e)][hd]
// where swz swaps bits 2<->3 within each 16-j group (PI trick, round-5 verified:
// same permutation is implicitly applied to P's natural register order).
// grid (L/64, BH), block 256.
__global__ __launch_bounds__(256) void pack_v(
    const bf16* __restrict__ vh, bf16* __restrict__ Vp)
{
    __shared__ __align__(16) bf16 tile[64][72];
    const int bh = blockIdx.y, l0 = blockIdx.x * 64;
    const bf16* src = vh + (size_t)bh * L_ * HD_;
    bf16*       dst = Vp + (size_t)bh * 256 * 64 * 8;
    const int x = threadIdx.x;
#pragma unroll
    for (int m = 0; m < 2; m++) {
        const int s = m * 256 + x;
        const int l = s >> 3, c = s & 7;
        *(bf16x8*)(&tile[l][c * 8]) = *(const bf16x8*)(src + (size_t)(l0 + l) * HD_ + c * 8);
    }
    __syncthreads();
#pragma unroll
    for (int m = 0; m < 2; m++) {
        const int s = m * 256 + x;
        const int hd = s & 63, lc = s >> 6;   // hd fast -> coalesced 1KB store runs
        bf16x8 v;
#pragma unroll
        for (int e = 0; e < 8; e++) {
            const int p = lc * 8 + e;
            const int t = p & 15;
            const int tp = (t & 3) | ((t & 4) << 1) | ((t & 8) >> 1);  // swap bits 2,3
            v[e] = tile[(p & 48) | tp][hd];
        }
        *(bf16x8*)(dst + ((size_t)(l0 / 8 + lc) * 64 + hd) * 8) = v;
    }
}

// ---- flash attention, max-free (post-ReLU q,k => scores >= 0) ----
// qh pre-scaled by (1/sqrt(512))*log2(e).  Kp [BH][8][L][8], Vp [BH][256][64][8]
// (PI-swizzled).  Wave: 32 q-rows; block 4 waves = 128q; grid (16, 32) = 512
// blocks -> 2048 waves (8/CU).  K/V staged frag-major from panels (coalesced
// 512B runs), register prefetch one tile ahead.  S^T = K @ Q^T (C-layout);
// P enters PV in natural register order (PI-matched with V) -- round-5 verified.
// Output: O-panels Op [64][M_][8] for the final projection.
__global__ __launch_bounds__(256) void attn_kernel(
    const bf16* __restrict__ qh, const bf16* __restrict__ Kp,
    const bf16* __restrict__ Vp, bf16* __restrict__ Op)
{
    const int w    = threadIdx.x >> 6;
    const int lane = threadIdx.x & 63;
    const int l31  = lane & 31;
    const int hi   = lane >> 5;
    const int bh   = blockIdx.y;
    const int qb   = blockIdx.x * 128 + w * 32;

    const bf16* Q   = qh + (size_t)bh * L_ * HD_;
    const bf16* Kpb = Kp + (size_t)bh * 8 * L_ * 8;
    const bf16* Vpb = Vp + (size_t)bh * 256 * 64 * 8;

    __shared__ __align__(16) bf16 Kbuf[8][64][8];   // f = ks*2 + jt
    __shared__ __align__(16) bf16 Vbuf[8][64][8];   // f = ksj*2 + hdf
    __shared__ float Lw[4][32];

    // Q fragments (B-operand): n=q=l31, k = ks*16 + hi*8 + e
    bf16x8 qf[4];
#pragma unroll
    for (int ks = 0; ks < 4; ks++)
        qf[ks] = *(const bf16x8*)(Q + (size_t)(qb + l31) * HD_ + ks * 16 + hi * 8);

    f32x16 o[2];
#pragma unroll
    for (int hf = 0; hf < 2; hf++)
#pragma unroll
        for (int r = 0; r < 16; r++) o[hf][r] = 0.0f;
    float lsum = 0.0f;

    auto kga = [&](int f, int j0) {   // K f: ks=f>>1, jt=f&1; lane-contiguous
        return Kpb + ((size_t)((f >> 1) * 2 + hi) * L_ + j0 + (f & 1) * 32 + l31) * 8;
    };
    auto vga = [&](int f, int j0) {   // V f: ksj=f>>1, hdf=f&1; lane-contiguous
        return Vpb + ((size_t)(j0 / 8 + (f >> 1) * 2 + hi) * 64 + (f & 1) * 32 + l31) * 8;
    };

    bf16x8 kr[2], vr[2];
#pragma unroll
    for (int i = 0; i < 2; i++) {
        kr[i] = *(const bf16x8*)kga(w * 2 + i, 0);
        vr[i] = *(const bf16x8*)vga(w * 2 + i, 0);
    }

    for (int j0 = 0; j0 < L_; j0 += 64) {
        __syncthreads();
#pragma unroll
        for (int i = 0; i < 2; i++) {
            *(bf16x8*)(&Kbuf[w * 2 + i][lane][0]) = kr[i];
            *(bf16x8*)(&Vbuf[w * 2 + i][lane][0]) = vr[i];
        }
        __syncthreads();
        const int jn = (j0 + 64 < L_) ? j0 + 64 : j0;   // last prefetch redundant
#pragma unroll
        for (int i = 0; i < 2; i++) {
            kr[i] = *(const bf16x8*)kga(w * 2 + i, jn);
            vr[i] = *(const bf16x8*)vga(w * 2 + i, jn);
        }

        // S^T[j][q] (C-layout: col=q=l31, row=j)
        f32x16 s[2];
#pragma unroll
        for (int jt = 0; jt < 2; jt++)
#pragma unroll
            for (int r = 0; r < 16; r++) s[jt][r] = 0.0f;
#pragma unroll
        for (int ks = 0; ks < 4; ks++)
#pragma unroll
            for (int jt = 0; jt < 2; jt++) {
                const bf16x8 kfr = *(const bf16x8*)(&Kbuf[ks * 2 + jt][lane][0]);
                s[jt] = mfma32(kfr, qf[ks], s[jt]);
            }

        // exp2 in place + per-lane row-sum partials (lane owns q=l31).
#pragma unroll
        for (int jt = 0; jt < 2; jt++)
#pragma unroll
            for (int r = 0; r < 16; r++) {
                const float e = __builtin_amdgcn_exp2f(s[jt][r]);
                s[jt][r] = e;
                lsum += e;
            }

        // O += P @ V (P natural-order regs, PI-matched with V).
#pragma unroll
        for (int ksj = 0; ksj < 4; ksj++) {
            const f32x16& sv = s[ksj >> 1];
            const int b8 = (ksj & 1) * 8;
            bf16x8 pf;
#pragma unroll
            for (int u = 0; u < 8; u++) pf[u] = (bf16)sv[b8 + u];
#pragma unroll
            for (int hf = 0; hf < 2; hf++) {
                const bf16x8 vfr = *(const bf16x8*)(&Vbuf[ksj * 2 + hf][lane][0]);
                o[hf] = mfma32(pf, vfr, o[hf]);
            }
        }
    }

    // Row sums: hi halves hold disjoint j; combine + broadcast via LDS (in-wave).
    lsum += __shfl_xor(lsum, 32);
    if (hi == 0) Lw[w][l31] = lsum;
    asm volatile("s_waitcnt lgkmcnt(0)" ::: "memory");

    const int b = bh >> 3, h = bh & 7;
#pragma unroll
    for (int r = 0; r < 16; r++) {
        const int rl = (r & 3) + 8 * (r >> 2) + 4 * hi;
        const float inv = 1.0f / Lw[w][rl];
        const int m = b * L_ + qb + rl;
#pragma unroll
        for (int hf = 0; hf < 2; hf++) {
            const int col = h * HD_ + hf * 32 + l31;
            Op[((size_t)(col >> 3) * M_ + m) * 8 + (col & 7)] = (bf16)(o[hf][r] * inv);
        }
    }
}

extern "C" void kernel_launch(void* const* d_in, const int* in_sizes, int n_in,
                              void* d_out, int out_size, void* d_ws, size_t ws_size,
                              hipStream_t stream)
{
    (void)in_sizes; (void)n_in; (void)out_size; (void)ws_size;
    const float* q  = (const float*)d_in[0];
    const float* k  = (const float*)d_in[1];
    const float* v  = (const float*)d_in[2];
    const float* Wq = (const float*)d_in[3];
    const float* bq = (const float*)d_in[4];
    const float* Wk = (const float*)d_in[5];
    const float* bk = (const float*)d_in[6];
    const float* Wv = (const float*)d_in[7];
    const float* bv = (const float*)d_in[8];
    const float* Wo = (const float*)d_in[9];
    const float* bo = (const float*)d_in[10];
    float* out = (float*)d_out;

    // Workspace (26 MB of ws) + Kp parked in the unused half-of-d_out window
    // (Kp is dead before the final projection rewrites d_out).
    char* ws = (char*)d_ws;
    const size_t SZ = (size_t)8 * 1024 * 1024;
    bf16* P0 = (bf16*)(ws);            // X panels (per proj), later Vp
    bf16* qh = (bf16*)(ws + SZ);       // [B,H,L,HD]
    bf16* vh = (bf16*)(ws + 2 * SZ);   // [B,H,L,HD]; later reused as Op
    bf16* Wp = (bf16*)(ws + 3 * SZ);   // 4 x 0.5 MB weight panels
    bf16* Kp = (bf16*)(d_out);         // 8 MB K panels inside the 16 MB output
    bf16* Vp = P0;                     // V panels overwrite X panels (dead)
    bf16* Ob = vh;                     // O panels overwrite vh (dead)

    bf16* Wqp = Wp, *Wkp = Wp + (size_t)64 * 512 * 8, *Wvp = Wp + (size_t)2 * 64 * 512 * 8,
        * Wop = Wp + (size_t)3 * 64 * 512 * 8;

    const float SCALE_LOG2E = 0.06377946282349575f;  // (1/sqrt(512))*log2(e)

    dim3 pb(256);
    pack_w<<<dim3(8, 8, 4), pb, 0, stream>>>(Wq, Wk, Wv, Wo, Wp);

    dim3 pgrid(M_ / 128, D_ / 64);
    pack_x<<<dim3(M_ / 64, 8), pb, 0, stream>>>(q, P0, M_);
    proj_kernel<0><<<pgrid, pb, 0, stream>>>(P0, Wqp, bq, qh, SCALE_LOG2E);

    pack_x<<<dim3(M_ / 64, 8), pb, 0, stream>>>(k, P0, M_);
    proj_kernel<1><<<pgrid, pb, 0, stream>>>(P0, Wkp, bk, Kp, 1.0f);

    pack_x<<<dim3(M_ / 64, 8), pb, 0, stream>>>(v, P0, M_);
    proj_kernel<0><<<pgrid, pb, 0, stream>>>(P0, Wvp, bv, vh, 1.0f);

    pack_v<<<dim3(L_ / 64, B_ * H_), pb, 0, stream>>>(vh, Vp);

    attn_kernel<<<dim3(L_ / 128, B_ * H_), pb, 0, stream>>>(qh, Kp, Vp, Ob);

    proj_kernel<2><<<pgrid, pb, 0, stream>>>(Ob, Wop, bo, out, 1.0f);
}

// Round 7
// 210.556 us; speedup vs baseline: 2.9074x; 1.0241x over previous
//
#include <hip/hip_runtime.h>
#include <hip/hip_bf16.h>

#define B_  4
#define L_  2048
#define D_  512
#define H_  8
#define HD_ 64
#define M_  (B_ * L_)   // 8192

typedef __bf16 bf16;
typedef __attribute__((ext_vector_type(8)))  __bf16 bf16x8;
typedef __attribute__((ext_vector_type(4)))  __bf16 bf16x4;
typedef __attribute__((ext_vector_type(16))) float  f32x16;

__device__ __forceinline__ f32x16 mfma32(bf16x8 a, bf16x8 b, f32x16 c) {
    return __builtin_amdgcn_mfma_f32_32x32x16_bf16(a, b, c, 0, 0, 0);
}

// ---- pack: src fp32 [R][512] -> dst bf16 panels [64][R][8] ----
__device__ __forceinline__ void pack_body(const float* __restrict__ src,
                                          bf16* __restrict__ dst, int R,
                                          int m0, int k0)
{
    __shared__ __align__(16) bf16 tile[64][76];
    const int t = threadIdx.x;
#pragma unroll
    for (int rep = 0; rep < 4; rep++) {
        const int idx = rep * 256 + t;
        const int r = idx >> 4, c4 = idx & 15;
        const float4 f = *(const float4*)(src + (size_t)(m0 + r) * 512 + k0 + c4 * 4);
        bf16x4 v; v[0] = (bf16)f.x; v[1] = (bf16)f.y; v[2] = (bf16)f.z; v[3] = (bf16)f.w;
        *(bf16x4*)(&tile[r][c4 * 4]) = v;
    }
    __syncthreads();
#pragma unroll
    for (int rep = 0; rep < 2; rep++) {
        const int s = rep * 256 + t;
        const int ml = s & 63, kpl = s >> 6;
        const bf16x4 lo = *(const bf16x4*)(&tile[ml][kpl * 8]);
        const bf16x4 hi4 = *(const bf16x4*)(&tile[ml][kpl * 8 + 4]);
        bf16x8 v;
#pragma unroll
        for (int e = 0; e < 4; e++) { v[e] = lo[e]; v[e + 4] = hi4[e]; }
        *(bf16x8*)(dst + ((size_t)(k0 / 8 + kpl) * R + m0 + ml) * 8) = v;
    }
}

// z<4: weight z -> Wp+z*256K (R=512, only blockIdx.x<8 active); z=4: q->P0; z=5: k->P1.
// grid (128, 8, 6), block 256.
__global__ __launch_bounds__(256) void pack_all(
    const float* __restrict__ q, const float* __restrict__ k,
    const float* __restrict__ W0, const float* __restrict__ W1,
    const float* __restrict__ W2, const float* __restrict__ W3,
    bf16* __restrict__ Wp, bf16* __restrict__ P0, bf16* __restrict__ P1)
{
    const int z = blockIdx.z;
    if (z < 4) {
        if (blockIdx.x >= 8) return;
        const float* src = z == 0 ? W0 : z == 1 ? W1 : z == 2 ? W2 : W3;
        pack_body(src, Wp + (size_t)z * 64 * 512 * 8, 512, blockIdx.x * 64, blockIdx.y * 64);
    } else {
        pack_body(z == 4 ? q : k, z == 4 ? P0 : P1, M_, blockIdx.x * 64, blockIdx.y * 64);
    }
}

// grid (128, 8): single fp32 input -> panels (for V, after P1 frees up)
__global__ __launch_bounds__(256) void pack_x(const float* __restrict__ src,
                                              bf16* __restrict__ dst)
{
    pack_body(src, dst, M_, blockIdx.x * 64, blockIdx.y * 64);
}

// ---- projection: relu(Xp @ Wp^T + b) (*postmul), double-buffered LDS ----
// Xp [64][M_][8], Wp [64][512][8] bf16 panels.  Block 256/4 waves, tile
// 128m x 64n, k-step 64, ONE barrier per k-step (dbuf).  grid (64, 8, NZ).
// mode 0: bf16 [B,H,L,HD];  1: K-panels [BH][8][L][8];
// 2: fp32 [M,512];          3: V-panels [BH][256][64][8] PI-swizzled.
struct PJob {
    const bf16* X; const bf16* W; const float* bias; void* out;
    float postmul; int mode;
};

__global__ __launch_bounds__(256) void proj_kernel(PJob j0, PJob j1)
{
    const PJob jb = (blockIdx.z == 0) ? j0 : j1;
    const int w    = threadIdx.x >> 6;
    const int lane = threadIdx.x & 63;
    const int l31  = lane & 31;
    const int hi   = lane >> 5;
    const int m0 = blockIdx.x * 128;
    const int n0 = blockIdx.y * 64;
    const int mh = w & 1;
    const int nh = w >> 1;

    __shared__ __align__(16) bf16 Ab[2][16][64][8];   // 32 KB
    __shared__ __align__(16) bf16 Bb[2][8][64][8];    // 16 KB

    f32x16 acc[2];
#pragma unroll
    for (int mi = 0; mi < 2; mi++)
#pragma unroll
        for (int r = 0; r < 16; r++) acc[mi][r] = 0.0f;

    auto ldA = [&](int f, int k0) -> bf16x8 {
        return *(const bf16x8*)(jb.X + ((size_t)((k0 >> 3) + (f >> 2) * 2 + hi) * M_
                                        + m0 + (f & 3) * 32 + l31) * 8);
    };
    auto ldB = [&](int f, int k0) -> bf16x8 {
        return *(const bf16x8*)(jb.W + ((size_t)((k0 >> 3) + (f >> 1) * 2 + hi) * 512
                                        + n0 + (f & 1) * 32 + l31) * 8);
    };

    bf16x8 ra[4], rb[2];
#pragma unroll
    for (int i = 0; i < 4; i++) ra[i] = ldA(w * 4 + i, 0);
#pragma unroll
    for (int i = 0; i < 2; i++) rb[i] = ldB(w * 2 + i, 0);
#pragma unroll
    for (int i = 0; i < 4; i++) *(bf16x8*)(&Ab[0][w * 4 + i][lane][0]) = ra[i];
#pragma unroll
    for (int i = 0; i < 2; i++) *(bf16x8*)(&Bb[0][w * 2 + i][lane][0]) = rb[i];
    __syncthreads();

    for (int it = 0; it < 8; it++) {
        const int cur = it & 1;
        if (it < 7) {
            const int kn = (it + 1) * 64;
#pragma unroll
            for (int i = 0; i < 4; i++) ra[i] = ldA(w * 4 + i, kn);
#pragma unroll
            for (int i = 0; i < 2; i++) rb[i] = ldB(w * 2 + i, kn);
        }
#pragma unroll
        for (int ks = 0; ks < 4; ks++) {
            const bf16x8 bfr = *(const bf16x8*)(&Bb[cur][ks * 2 + nh][lane][0]);
#pragma unroll
            for (int mi = 0; mi < 2; mi++) {
                const bf16x8 afr = *(const bf16x8*)(&Ab[cur][ks * 4 + mh * 2 + mi][lane][0]);
                acc[mi] = mfma32(afr, bfr, acc[mi]);
            }
        }
        if (it < 7) {
#pragma unroll
            for (int i = 0; i < 4; i++) *(bf16x8*)(&Ab[1 - cur][w * 4 + i][lane][0]) = ra[i];
#pragma unroll
            for (int i = 0; i < 2; i++) *(bf16x8*)(&Bb[1 - cur][w * 2 + i][lane][0]) = rb[i];
            __syncthreads();
        }
    }

    const int col = n0 + nh * 32 + l31;
    const float bn = jb.bias[col];
    const int mode = jb.mode;
#pragma unroll
    for (int mi = 0; mi < 2; mi++)
#pragma unroll
        for (int r = 0; r < 16; r++) {
            const int row = m0 + (mh * 2 + mi) * 32 + (r & 3) + 8 * (r >> 2) + 4 * hi;
            float v = fmaxf(acc[mi][r] + bn, 0.0f);
            if (mode == 2) {
                ((float*)jb.out)[(size_t)row * D_ + col] = v;
            } else {
                v *= jb.postmul;
                const int b = row >> 11, l = row & (L_ - 1);
                const int h = col >> 6,  hd = col & (HD_ - 1);
                const int bh = b * H_ + h;
                size_t idx;
                if (mode == 0) {
                    idx = ((size_t)bh * L_ + l) * HD_ + hd;
                } else if (mode == 1) {       // K panels [bh][hd>>3][l][hd&7]
                    idx = (((size_t)bh * 8 + (hd >> 3)) * L_ + l) * 8 + (hd & 7);
                } else {                      // mode 3: V panels, PI-swizzled j
                    const int swzl = (l & ~15) | (l & 3) | ((l & 4) << 1) | ((l & 8) >> 1);
                    idx = (((size_t)bh * 256 + (swzl >> 3)) * 64 + hd) * 8 + (swzl & 7);
                }
                ((bf16*)jb.out)[idx] = (bf16)v;
            }
        }
}

// ---- flash attention, max-free (post-ReLU q,k => scores >= 0) ----
// qh pre-scaled by (1/sqrt(512))*log2(e).  Kp [BH][8][L][8], Vp [BH][256][64][8]
// (PI-swizzled, matching P's natural register order -- round-5/6 verified).
// Block: 2 waves x 32q = 64q; grid (32, 32) = 1024 blocks (4/CU, 8 waves/CU).
// Double-buffered K/V staging: ONE barrier per 64-j tile; S-acc starts from a
// constant zero register (no per-tile zeroing); loop-carried pointer bumps.
__global__ __launch_bounds__(128) void attn_kernel(
    const bf16* __restrict__ qh, const bf16* __restrict__ Kp,
    const bf16* __restrict__ Vp, bf16* __restrict__ Op)
{
    const int w    = threadIdx.x >> 6;   // 0..1
    const int lane = threadIdx.x & 63;
    const int l31  = lane & 31;
    const int hi   = lane >> 5;
    const int bh   = blockIdx.y;
    const int qb   = blockIdx.x * 64 + w * 32;

    const bf16* Q   = qh + (size_t)bh * L_ * HD_;
    const bf16* Kpb = Kp + (size_t)bh * 8 * L_ * 8;
    const bf16* Vpb = Vp + (size_t)bh * 256 * 64 * 8;

    __shared__ __align__(16) bf16 Kb[2][8][64][8];   // 16 KB
    __shared__ __align__(16) bf16 Vb[2][8][64][8];   // 16 KB
    __shared__ float Lw[2][32];

    bf16x8 qf[4];
#pragma unroll
    for (int ks = 0; ks < 4; ks++)
        qf[ks] = *(const bf16x8*)(Q + (size_t)(qb + l31) * HD_ + ks * 16 + hi * 8);

    f32x16 zz;
#pragma unroll
    for (int r = 0; r < 16; r++) zz[r] = 0.0f;
    f32x16 o0 = zz, o1 = zz;
    float lsum = 0.0f;

    // staging pointers: wave stages frags f = w*4+i (i<4) of both K and V
    const bf16* kp[4];
    const bf16* vp[4];
#pragma unroll
    for (int i = 0; i < 4; i++) {
        const int f = w * 4 + i;
        kp[i] = Kpb + ((size_t)((f >> 1) * 2 + hi) * L_ + (f & 1) * 32 + l31) * 8;
        vp[i] = Vpb + ((size_t)((f >> 1) * 2 + hi) * 64 + (f & 1) * 32 + l31) * 8;
    }

    bf16x8 kr[4], vr[4];
#pragma unroll
    for (int i = 0; i < 4; i++) {
        kr[i] = *(const bf16x8*)kp[i]; kp[i] += 512;    // next tile: +64 rows
        vr[i] = *(const bf16x8*)vp[i]; vp[i] += 4096;   // next tile: +8 jq panels
    }
#pragma unroll
    for (int i = 0; i < 4; i++) {
        *(bf16x8*)(&Kb[0][w * 4 + i][lane][0]) = kr[i];
        *(bf16x8*)(&Vb[0][w * 4 + i][lane][0]) = vr[i];
    }
    __syncthreads();

    for (int t = 0; t < 32; t++) {
        const int cur = t & 1;
        if (t < 31) {
#pragma unroll
            for (int i = 0; i < 4; i++) {
                kr[i] = *(const bf16x8*)kp[i]; kp[i] += 512;
                vr[i] = *(const bf16x8*)vp[i]; vp[i] += 4096;
            }
        }

        // S^T = K @ Q^T, C-layout; acc seeded from constant zero reg.
        f32x16 s0 = mfma32(*(const bf16x8*)(&Kb[cur][0][lane][0]), qf[0], zz);
        f32x16 s1 = mfma32(*(const bf16x8*)(&Kb[cur][1][lane][0]), qf[0], zz);
#pragma unroll
        for (int ks = 1; ks < 4; ks++) {
            s0 = mfma32(*(const bf16x8*)(&Kb[cur][ks * 2 + 0][lane][0]), qf[ks], s0);
            s1 = mfma32(*(const bf16x8*)(&Kb[cur][ks * 2 + 1][lane][0]), qf[ks], s1);
        }

        // half 0: exp2(s0) -> P frags (natural order, PI-matched) -> PV ksj 0,1
#pragma unroll
        for (int r = 0; r < 16; r++) {
            const float e = __builtin_amdgcn_exp2f(s0[r]);
            s0[r] = e; lsum += e;
        }
        {
            bf16x8 pf0, pf1;
#pragma unroll
            for (int u = 0; u < 8; u++) { pf0[u] = (bf16)s0[u]; pf1[u] = (bf16)s0[8 + u]; }
            o0 = mfma32(pf0, *(const bf16x8*)(&Vb[cur][0][lane][0]), o0);
            o1 = mfma32(pf0, *(const bf16x8*)(&Vb[cur][1][lane][0]), o1);
            o0 = mfma32(pf1, *(const bf16x8*)(&Vb[cur][2][lane][0]), o0);
            o1 = mfma32(pf1, *(const bf16x8*)(&Vb[cur][3][lane][0]), o1);
        }
        // half 1: exp2(s1) -> PV ksj 2,3
#pragma unroll
        for (int r = 0; r < 16; r++) {
            const float e = __builtin_amdgcn_exp2f(s1[r]);
            s1[r] = e; lsum += e;
        }
        {
            bf16x8 pf2, pf3;
#pragma unroll
            for (int u = 0; u < 8; u++) { pf2[u] = (bf16)s1[u]; pf3[u] = (bf16)s1[8 + u]; }
            o0 = mfma32(pf2, *(const bf16x8*)(&Vb[cur][4][lane][0]), o0);
            o1 = mfma32(pf2, *(const bf16x8*)(&Vb[cur][5][lane][0]), o1);
            o0 = mfma32(pf3, *(const bf16x8*)(&Vb[cur][6][lane][0]), o0);
            o1 = mfma32(pf3, *(const bf16x8*)(&Vb[cur][7][lane][0]), o1);
        }

        if (t < 31) {
#pragma unroll
            for (int i = 0; i < 4; i++) {
                *(bf16x8*)(&Kb[1 - cur][w * 4 + i][lane][0]) = kr[i];
                *(bf16x8*)(&Vb[1 - cur][w * 4 + i][lane][0]) = vr[i];
            }
            __syncthreads();
        }
    }

    // Row sums: hi halves hold disjoint j; combine, broadcast via LDS (in-wave).
    lsum += __shfl_xor(lsum, 32);
    if (hi == 0) Lw[w][l31] = lsum;
    asm volatile("s_waitcnt lgkmcnt(0)" ::: "memory");

    const int b = bh >> 3, h = bh & 7;
#pragma unroll
    for (int r = 0; r < 16; r++) {
        const int rl = (r & 3) + 8 * (r >> 2) + 4 * hi;
        const float inv = 1.0f / Lw[w][rl];
        const int m = b * L_ + qb + rl;
        {
            const int col = h * HD_ + l31;
            Op[((size_t)(col >> 3) * M_ + m) * 8 + (col & 7)] = (bf16)(o0[r] * inv);
        }
        {
            const int col = h * HD_ + 32 + l31;
            Op[((size_t)(col >> 3) * M_ + m) * 8 + (col & 7)] = (bf16)(o1[r] * inv);
        }
    }
}

extern "C" void kernel_launch(void* const* d_in, const int* in_sizes, int n_in,
                              void* d_out, int out_size, void* d_ws, size_t ws_size,
                              hipStream_t stream)
{
    (void)in_sizes; (void)n_in; (void)out_size; (void)ws_size;
    const float* q  = (const float*)d_in[0];
    const float* k  = (const float*)d_in[1];
    const float* v  = (const float*)d_in[2];
    const float* Wq = (const float*)d_in[3];
    const float* bq = (const float*)d_in[4];
    const float* Wk = (const float*)d_in[5];
    const float* bk = (const float*)d_in[6];
    const float* Wv = (const float*)d_in[7];
    const float* bv = (const float*)d_in[8];
    const float* Wo = (const float*)d_in[9];
    const float* bo = (const float*)d_in[10];
    float* out = (float*)d_out;

    // ws (26 MB): P0 @0, P1 @8M, Wp @16M (2 MB), Vp @18M (8 MB).
    // d_out (16 MB): qh @0 (8 MB), Kp @8M (8 MB) -- both dead before the final
    // projection overwrites d_out with the real output.
    char* ws = (char*)d_ws;
    const size_t MB = 1024 * 1024;
    bf16* P0  = (bf16*)(ws);
    bf16* P1  = (bf16*)(ws + 8 * MB);
    bf16* Wp  = (bf16*)(ws + 16 * MB);
    bf16* Vp  = (bf16*)(ws + 18 * MB);
    bf16* qh  = (bf16*)(d_out);
    bf16* Kp  = (bf16*)((char*)d_out + 8 * MB);
    bf16* Opb = P0;   // attn output panels reuse P0 (Xq dead)

    bf16* Wqp = Wp;
    bf16* Wkp = Wp + (size_t)64 * 512 * 8;
    bf16* Wvp = Wp + (size_t)2 * 64 * 512 * 8;
    bf16* Wop = Wp + (size_t)3 * 64 * 512 * 8;

    const float SCALE_LOG2E = 0.06377946282349575f;  // (1/sqrt(512))*log2(e)

    dim3 pb(256);
    pack_all<<<dim3(128, 8, 6), pb, 0, stream>>>(q, k, Wq, Wk, Wv, Wo, Wp, P0, P1);

    PJob jq{P0, Wqp, bq, qh, SCALE_LOG2E, 0};
    PJob jk{P1, Wkp, bk, Kp, 1.0f, 1};
    proj_kernel<<<dim3(64, 8, 2), pb, 0, stream>>>(jq, jk);

    pack_x<<<dim3(128, 8), pb, 0, stream>>>(v, P1);   // P1 (Xk) dead -> Xv panels

    PJob jv{P1, Wvp, bv, Vp, 1.0f, 3};
    proj_kernel<<<dim3(64, 8, 1), pb, 0, stream>>>(jv, jv);

    attn_kernel<<<dim3(L_ / 64, B_ * H_), dim3(128), 0, stream>>>(qh, Kp, Vp, Opb);

    PJob jo{Opb, Wop, bo, out, 1.0f, 2};
    proj_kernel<<<dim3(64, 8, 1), pb, 0, stream>>>(jo, jo);
}

// Round 8
// 201.239 us; speedup vs baseline: 3.0420x; 1.0463x over previous
//
#include <hip/hip_runtime.h>
#include <hip/hip_bf16.h>

#define B_  4
#define L_  2048
#define D_  512
#define H_  8
#define HD_ 64
#define M_  (B_ * L_)   // 8192

typedef __bf16 bf16;
typedef __attribute__((ext_vector_type(8)))  __bf16 bf16x8;
typedef __attribute__((ext_vector_type(4)))  __bf16 bf16x4;
typedef __attribute__((ext_vector_type(16))) float  f32x16;

__device__ __forceinline__ f32x16 mfma32(bf16x8 a, bf16x8 b, f32x16 c) {
    return __builtin_amdgcn_mfma_f32_32x32x16_bf16(a, b, c, 0, 0, 0);
}

// ---- pack: src fp32 [R][512] -> dst bf16 panels [64][R][8] ----
__device__ __forceinline__ void pack_body(const float* __restrict__ src,
                                          bf16* __restrict__ dst, int R,
                                          int m0, int k0)
{
    __shared__ __align__(16) bf16 tile[64][76];
    const int t = threadIdx.x;
#pragma unroll
    for (int rep = 0; rep < 4; rep++) {
        const int idx = rep * 256 + t;
        const int r = idx >> 4, c4 = idx & 15;
        const float4 f = *(const float4*)(src + (size_t)(m0 + r) * 512 + k0 + c4 * 4);
        bf16x4 v; v[0] = (bf16)f.x; v[1] = (bf16)f.y; v[2] = (bf16)f.z; v[3] = (bf16)f.w;
        *(bf16x4*)(&tile[r][c4 * 4]) = v;
    }
    __syncthreads();
#pragma unroll
    for (int rep = 0; rep < 2; rep++) {
        const int s = rep * 256 + t;
        const int ml = s & 63, kpl = s >> 6;
        const bf16x4 lo = *(const bf16x4*)(&tile[ml][kpl * 8]);
        const bf16x4 hi4 = *(const bf16x4*)(&tile[ml][kpl * 8 + 4]);
        bf16x8 v;
#pragma unroll
        for (int e = 0; e < 4; e++) { v[e] = lo[e]; v[e + 4] = hi4[e]; }
        *(bf16x8*)(dst + ((size_t)(k0 / 8 + kpl) * R + m0 + ml) * 8) = v;
    }
}

// z<4: weight z (blockIdx.x<8); z=4: q->P0; z=5: k->P1; z=6: v->P2.
// grid (128, 8, 7), block 256.
__global__ __launch_bounds__(256) void pack_all(
    const float* __restrict__ q, const float* __restrict__ k,
    const float* __restrict__ v,
    const float* __restrict__ W0, const float* __restrict__ W1,
    const float* __restrict__ W2, const float* __restrict__ W3,
    bf16* __restrict__ Wp, bf16* __restrict__ P0, bf16* __restrict__ P1,
    bf16* __restrict__ P2)
{
    const int z = blockIdx.z;
    if (z < 4) {
        if (blockIdx.x >= 8) return;
        const float* src = z == 0 ? W0 : z == 1 ? W1 : z == 2 ? W2 : W3;
        pack_body(src, Wp + (size_t)z * 64 * 512 * 8, 512, blockIdx.x * 64, blockIdx.y * 64);
    } else {
        const float* src = z == 4 ? q : z == 5 ? k : v;
        bf16* dst = z == 4 ? P0 : z == 5 ? P1 : P2;
        pack_body(src, dst, M_, blockIdx.x * 64, blockIdx.y * 64);
    }
}

// ---- projection: relu(Xp @ Wp^T + b) (*postmul) ----
// Panel inputs.  Block 256/4 waves, tile 128m x 64n, k-step 64, single
// LDS dbuf (1 barrier/k-step) + THREE register prefetch sets: load k-step
// it+3 while storing it+1 and computing it -> ~2.5 k-steps of latency cover.
// grid (64, 8, NZ).  mode 0: bf16 [B,H,L,HD]; 1: K-panels [BH][8][L][8];
// 2: fp32 [M,512]; 3: V-panels [BH][256][64][8] PI-swizzled.
struct PJob {
    const bf16* X; const bf16* W; const float* bias; void* out;
    float postmul; int mode;
};

__global__ __launch_bounds__(256, 3) void proj_kernel(PJob j0, PJob j1)
{
    const PJob jb = (blockIdx.z == 0) ? j0 : j1;
    const int w    = threadIdx.x >> 6;
    const int lane = threadIdx.x & 63;
    const int l31  = lane & 31;
    const int hi   = lane >> 5;
    const int m0 = blockIdx.x * 128;
    const int n0 = blockIdx.y * 64;
    const int mh = w & 1;
    const int nh = w >> 1;

    __shared__ __align__(16) bf16 Ab[2][16][64][8];   // 32 KB
    __shared__ __align__(16) bf16 Bb[2][8][64][8];    // 16 KB

    f32x16 acc[2];
#pragma unroll
    for (int mi = 0; mi < 2; mi++)
#pragma unroll
        for (int r = 0; r < 16; r++) acc[mi][r] = 0.0f;

    auto ldA = [&](int f, int k0) -> bf16x8 {
        return *(const bf16x8*)(jb.X + ((size_t)((k0 >> 3) + (f >> 2) * 2 + hi) * M_
                                        + m0 + (f & 3) * 32 + l31) * 8);
    };
    auto ldB = [&](int f, int k0) -> bf16x8 {
        return *(const bf16x8*)(jb.W + ((size_t)((k0 >> 3) + (f >> 1) * 2 + hi) * 512
                                        + n0 + (f & 1) * 32 + l31) * 8);
    };

    bf16x8 rA[3][4], rB[3][2];
#pragma unroll
    for (int i = 0; i < 4; i++) rA[0][i] = ldA(w * 4 + i, 0);
#pragma unroll
    for (int i = 0; i < 2; i++) rB[0][i] = ldB(w * 2 + i, 0);
#pragma unroll
    for (int i = 0; i < 4; i++) *(bf16x8*)(&Ab[0][w * 4 + i][lane][0]) = rA[0][i];
#pragma unroll
    for (int i = 0; i < 2; i++) *(bf16x8*)(&Bb[0][w * 2 + i][lane][0]) = rB[0][i];
#pragma unroll
    for (int s = 1; s < 3; s++) {
#pragma unroll
        for (int i = 0; i < 4; i++) rA[s][i] = ldA(w * 4 + i, s * 64);
#pragma unroll
        for (int i = 0; i < 2; i++) rB[s][i] = ldB(w * 2 + i, s * 64);
    }
    __syncthreads();

#pragma unroll
    for (int it = 0; it < 8; it++) {
        const int cur = it & 1;
        if (it < 5) {
            const int s = it % 3, kn = (it + 3) * 64;
#pragma unroll
            for (int i = 0; i < 4; i++) rA[s][i] = ldA(w * 4 + i, kn);
#pragma unroll
            for (int i = 0; i < 2; i++) rB[s][i] = ldB(w * 2 + i, kn);
        }
#pragma unroll
        for (int ks = 0; ks < 4; ks++) {
            const bf16x8 bfr = *(const bf16x8*)(&Bb[cur][ks * 2 + nh][lane][0]);
#pragma unroll
            for (int mi = 0; mi < 2; mi++) {
                const bf16x8 afr = *(const bf16x8*)(&Ab[cur][ks * 4 + mh * 2 + mi][lane][0]);
                acc[mi] = mfma32(afr, bfr, acc[mi]);
            }
        }
        if (it < 7) {
            const int s = (it + 1) % 3;
#pragma unroll
            for (int i = 0; i < 4; i++) *(bf16x8*)(&Ab[1 - cur][w * 4 + i][lane][0]) = rA[s][i];
#pragma unroll
            for (int i = 0; i < 2; i++) *(bf16x8*)(&Bb[1 - cur][w * 2 + i][lane][0]) = rB[s][i];
            __syncthreads();
        }
    }

    const int col = n0 + nh * 32 + l31;
    const float bn = jb.bias[col];
    const int mode = jb.mode;
#pragma unroll
    for (int mi = 0; mi < 2; mi++)
#pragma unroll
        for (int r = 0; r < 16; r++) {
            const int row = m0 + (mh * 2 + mi) * 32 + (r & 3) + 8 * (r >> 2) + 4 * hi;
            float v = fmaxf(acc[mi][r] + bn, 0.0f);
            if (mode == 2) {
                ((float*)jb.out)[(size_t)row * D_ + col] = v;
            } else {
                v *= jb.postmul;
                const int b = row >> 11, l = row & (L_ - 1);
                const int h = col >> 6,  hd = col & (HD_ - 1);
                const int bh = b * H_ + h;
                size_t idx;
                if (mode == 0) {
                    idx = ((size_t)bh * L_ + l) * HD_ + hd;
                } else if (mode == 1) {       // K panels [bh][hd>>3][l][hd&7]
                    idx = (((size_t)bh * 8 + (hd >> 3)) * L_ + l) * 8 + (hd & 7);
                } else {                      // mode 3: V panels, PI-swizzled j
                    const int swzl = (l & ~15) | (l & 3) | ((l & 4) << 1) | ((l & 8) >> 1);
                    idx = (((size_t)bh * 256 + (swzl >> 3)) * 64 + hd) * 8 + (swzl & 7);
                }
                ((bf16*)jb.out)[idx] = (bf16)v;
            }
        }
}

// ---- flash attention, max-free (post-ReLU q,k => scores >= 0) ----
// qh pre-scaled by (1/sqrt(512))*log2(e).  Kp [BH][8][L][8], Vp [BH][256][64][8]
// (PI-swizzled; matches P natural register order -- round-5/6/7 verified).
// Wave: 32q; block 2 waves = 64q; grid (32, 32) = 1024 blocks (4/CU, 8 w/CU).
// K fragments load DIRECTLY global->register (panels are lane-contiguous;
// L2-resident), prefetched 1 tile ahead -- no K LDS traffic at all.
// V staged via LDS dbuf with 2-tile-deep register prefetch, 1 barrier/tile.
// Row-sums via MFMA with ones-B-fragment: lacc[q][*] = sum_j P[q][j] lands in
// the same C-layout rows as o -- no VALU adds, no epilogue reduction.
__global__ __launch_bounds__(128, 2) void attn_kernel(
    const bf16* __restrict__ qh, const bf16* __restrict__ Kp,
    const bf16* __restrict__ Vp, bf16* __restrict__ Op)
{
    const int w    = threadIdx.x >> 6;   // 0..1
    const int lane = threadIdx.x & 63;
    const int l31  = lane & 31;
    const int hi   = lane >> 5;
    const int bh   = blockIdx.y;
    const int qb   = blockIdx.x * 64 + w * 32;

    const bf16* Q   = qh + (size_t)bh * L_ * HD_;
    const bf16* Kpb = Kp + (size_t)bh * 8 * L_ * 8;
    const bf16* Vpb = Vp + (size_t)bh * 256 * 64 * 8;

    __shared__ __align__(16) bf16 Vb[2][8][64][8];   // 16 KB

    bf16x8 qf[4];
#pragma unroll
    for (int ks = 0; ks < 4; ks++)
        qf[ks] = *(const bf16x8*)(Q + (size_t)(qb + l31) * HD_ + ks * 16 + hi * 8);

    f32x16 zz;
#pragma unroll
    for (int r = 0; r < 16; r++) zz[r] = 0.0f;
    f32x16 o0 = zz, o1 = zz, lacc = zz;
    bf16x8 ones;
#pragma unroll
    for (int u = 0; u < 8; u++) ones[u] = (bf16)1.0f;

    auto ldK = [&](int f, int t) -> bf16x8 {   // f: ks=f>>1, jt=f&1
        return *(const bf16x8*)(Kpb + ((size_t)((f >> 1) * 2 + hi) * L_
                                       + t * 64 + (f & 1) * 32 + l31) * 8);
    };
    auto ldV = [&](int f, int t) -> bf16x8 {   // f: ksj=f>>1, hdf=f&1
        return *(const bf16x8*)(Vpb + ((size_t)(t * 8 + (f >> 1) * 2 + hi) * 64
                                       + (f & 1) * 32 + l31) * 8);
    };

    bf16x8 kr[8], vr[2][4];
#pragma unroll
    for (int i = 0; i < 4; i++) vr[0][i] = ldV(w * 4 + i, 0);
#pragma unroll
    for (int i = 0; i < 4; i++) *(bf16x8*)(&Vb[0][w * 4 + i][lane][0]) = vr[0][i];
#pragma unroll
    for (int i = 0; i < 4; i++) vr[1][i] = ldV(w * 4 + i, 1);
#pragma unroll
    for (int i = 0; i < 4; i++) vr[0][i] = ldV(w * 4 + i, 2);
#pragma unroll
    for (int f = 0; f < 8; f++) kr[f] = ldK(f, 0);
    __syncthreads();

    auto tile_body = [&](int t, int cur, int nxt) {
        // S^T = K @ Q^T, C-layout; K operands straight from global-loaded regs.
        f32x16 s0 = mfma32(kr[0], qf[0], zz);
        f32x16 s1 = mfma32(kr[1], qf[0], zz);
#pragma unroll
        for (int ks = 1; ks < 4; ks++) {
            s0 = mfma32(kr[ks * 2 + 0], qf[ks], s0);
            s1 = mfma32(kr[ks * 2 + 1], qf[ks], s1);
        }
        if (t < 31) {
#pragma unroll
            for (int f = 0; f < 8; f++) kr[f] = ldK(f, t + 1);
        }

        // half 0: exp2 -> P frags (natural order, PI-matched) -> PV + row-sum
#pragma unroll
        for (int r = 0; r < 16; r++) s0[r] = __builtin_amdgcn_exp2f(s0[r]);
        {
            bf16x8 pf0, pf1;
#pragma unroll
            for (int u = 0; u < 8; u++) { pf0[u] = (bf16)s0[u]; pf1[u] = (bf16)s0[8 + u]; }
            o0   = mfma32(pf0, *(const bf16x8*)(&Vb[cur][0][lane][0]), o0);
            o1   = mfma32(pf0, *(const bf16x8*)(&Vb[cur][1][lane][0]), o1);
            lacc = mfma32(pf0, ones, lacc);
            o0   = mfma32(pf1, *(const bf16x8*)(&Vb[cur][2][lane][0]), o0);
            o1   = mfma32(pf1, *(const bf16x8*)(&Vb[cur][3][lane][0]), o1);
            lacc = mfma32(pf1, ones, lacc);
        }
        // half 1
#pragma unroll
        for (int r = 0; r < 16; r++) s1[r] = __builtin_amdgcn_exp2f(s1[r]);
        {
            bf16x8 pf2, pf3;
#pragma unroll
            for (int u = 0; u < 8; u++) { pf2[u] = (bf16)s1[u]; pf3[u] = (bf16)s1[8 + u]; }
            o0   = mfma32(pf2, *(const bf16x8*)(&Vb[cur][4][lane][0]), o0);
            o1   = mfma32(pf2, *(const bf16x8*)(&Vb[cur][5][lane][0]), o1);
            lacc = mfma32(pf2, ones, lacc);
            o0   = mfma32(pf3, *(const bf16x8*)(&Vb[cur][6][lane][0]), o0);
            o1   = mfma32(pf3, *(const bf16x8*)(&Vb[cur][7][lane][0]), o1);
            lacc = mfma32(pf3, ones, lacc);
        }

        if (t < 31) {
            // store tile t+1 (loaded 2 tiles ago), then refill with tile t+3
#pragma unroll
            for (int i = 0; i < 4; i++)
                *(bf16x8*)(&Vb[1 - cur][w * 4 + i][lane][0]) = vr[nxt][i];
            const int tn = (t + 3 < 32) ? t + 3 : 31;
#pragma unroll
            for (int i = 0; i < 4; i++) vr[nxt][i] = ldV(w * 4 + i, tn);
            __syncthreads();
        }
    };

    for (int tt = 0; tt < 16; tt++) {
        tile_body(2 * tt + 0, 0, 1);
        tile_body(2 * tt + 1, 1, 0);
    }

    // Epilogue: lacc rows carry this lane's q-row sums (all n-cols identical).
    const int b = bh >> 3, h = bh & 7;
#pragma unroll
    for (int r = 0; r < 16; r++) {
        const int rl = (r & 3) + 8 * (r >> 2) + 4 * hi;
        const float inv = 1.0f / lacc[r];
        const int m = b * L_ + qb + rl;
        const int c0 = h * HD_ + l31;
        Op[((size_t)(c0 >> 3) * M_ + m) * 8 + (c0 & 7)] = (bf16)(o0[r] * inv);
        const int c1 = c0 + 32;
        Op[((size_t)(c1 >> 3) * M_ + m) * 8 + (c1 & 7)] = (bf16)(o1[r] * inv);
    }
}

extern "C" void kernel_launch(void* const* d_in, const int* in_sizes, int n_in,
                              void* d_out, int out_size, void* d_ws, size_t ws_size,
                              hipStream_t stream)
{
    (void)in_sizes; (void)n_in; (void)out_size; (void)ws_size;
    const float* q  = (const float*)d_in[0];
    const float* k  = (const float*)d_in[1];
    const float* v  = (const float*)d_in[2];
    const float* Wq = (const float*)d_in[3];
    const float* bq = (const float*)d_in[4];
    const float* Wk = (const float*)d_in[5];
    const float* bk = (const float*)d_in[6];
    const float* Wv = (const float*)d_in[7];
    const float* bv = (const float*)d_in[8];
    const float* Wo = (const float*)d_in[9];
    const float* bo = (const float*)d_in[10];
    float* out = (float*)d_out;

    // ws (26 MB): P0 @0, P1 @8M, P2 @16M, Wp @24M (2 MB).
    // d_out (16 MB): qh @0, Kp @8M -- both dead before the final projection.
    // Vp overwrites P0 (Xq dead after proj_qk); Op overwrites P1 (Xk dead).
    char* ws = (char*)d_ws;
    const size_t MB = 1024 * 1024;
    bf16* P0  = (bf16*)(ws);
    bf16* P1  = (bf16*)(ws + 8 * MB);
    bf16* P2  = (bf16*)(ws + 16 * MB);
    bf16* Wp  = (bf16*)(ws + 24 * MB);
    bf16* qh  = (bf16*)(d_out);
    bf16* Kp  = (bf16*)((char*)d_out + 8 * MB);
    bf16* Vp  = P0;
    bf16* Opb = P1;

    bf16* Wqp = Wp;
    bf16* Wkp = Wp + (size_t)64 * 512 * 8;
    bf16* Wvp = Wp + (size_t)2 * 64 * 512 * 8;
    bf16* Wop = Wp + (size_t)3 * 64 * 512 * 8;

    const float SCALE_LOG2E = 0.06377946282349575f;  // (1/sqrt(512))*log2(e)

    dim3 pb(256);
    pack_all<<<dim3(128, 8, 7), pb, 0, stream>>>(q, k, v, Wq, Wk, Wv, Wo,
                                                 Wp, P0, P1, P2);

    PJob jq{P0, Wqp, bq, qh, SCALE_LOG2E, 0};
    PJob jk{P1, Wkp, bk, Kp, 1.0f, 1};
    proj_kernel<<<dim3(64, 8, 2), pb, 0, stream>>>(jq, jk);

    PJob jv{P2, Wvp, bv, Vp, 1.0f, 3};
    proj_kernel<<<dim3(64, 8, 1), pb, 0, stream>>>(jv, jv);

    attn_kernel<<<dim3(32, 32), dim3(128), 0, stream>>>(qh, Kp, Vp, Opb);

    PJob jo{Opb, Wop, bo, out, 1.0f, 2};
    proj_kernel<<<dim3(64, 8, 1), pb, 0, stream>>>(jo, jo);
}